// Round 1
// baseline (1575.888 us; speedup 1.0000x reference)
//
#include <hip/hip_runtime.h>

// RelationAwareAttention: BS=4,H=8,L=1024,D=64,P=513, fp32.
// out = [attn_sum (B,H,L,D) | p_attn (B,H,L,L)] flat fp32.
//
// One fused kernel. Block = 256 threads handles (b, h, 16-row i-tile):
//   P0: compute score_r rows (Q[b,0] . relation^T) into sR[16][513]   (LDS)
//   P2: QK^T into sS[16][1024] via swizzled K tiles                    (LDS)
//   P3: fixup: s = (qk + sR[pm])*0.125, mask==0 -> -1e9   (coalesced pm/mask)
//   P4: row softmax (16 lanes/row, shfl reduce)
//   P5: write p_attn (float4, coalesced) + scatter p into buckets (sR reuse)
//   P6: attn = p@V + buckets@relation, write attn_sum

#define BSZ 4
#define NH 8
#define LSEQ 1024
#define DH 64
#define NP 513
#define TI 16
#define NT 256

#define SQ_STR 68     // Q rows, 16B-aligned rows, bank-staggered
#define SS_STR 1028   // score rows, 16B-aligned, bank-staggered
#define SR_STR 513    // score_r / bucket rows (odd -> gather spreads banks)

__global__ __launch_bounds__(NT, 1) void raa_kernel(
    const float* __restrict__ Q, const float* __restrict__ K,
    const float* __restrict__ V, const float* __restrict__ REL,
    const int* __restrict__ PM, const int* __restrict__ MASK,
    float* __restrict__ OUT_A, float* __restrict__ OUT_P)
{
    __shared__ float sS[TI * SS_STR];   // 65.8 KB scores
    __shared__ float sT[64 * 64];       // 16 KB K(swz)/V/rel tile
    __shared__ float sQ[TI * SQ_STR];   // 4.3 KB
    __shared__ float sR[TI * SR_STR];   // 32.8 KB score_r, reused as buckets

    const int tid = threadIdx.x;
    const int it  = blockIdx.x;
    const int h   = blockIdx.y;
    const int b   = blockIdx.z;
    const int i0  = it * TI;

    const int r   = tid >> 4;   // 0..15 local row
    const int l16 = tid & 15;

    const float* Qb0 = Q + ((size_t)b * NH + 0) * LSEQ * DH;
    const float* Qbh = Q + ((size_t)b * NH + h) * LSEQ * DH;
    const float* Kbh = K + ((size_t)b * NH + h) * LSEQ * DH;
    const float* Vbh = V + ((size_t)b * NH + h) * LSEQ * DH;
    const float* RELb = REL + (size_t)b * NP * DH;
    const int*   PMb  = PM  + (size_t)b * LSEQ * LSEQ;
    const int*   MKb  = MASK + (size_t)b * LSEQ * LSEQ;

    // ---------- P0: score_r rows from Q head 0 ----------
    for (int idx = tid; idx < TI * DH; idx += NT) {
        int rr = idx >> 6, kk = idx & 63;
        sQ[rr * SQ_STR + kk] = Qb0[(size_t)(i0 + rr) * DH + kk];
    }
    __syncthreads();

    for (int pt = 0; pt < 9; ++pt) {
        for (int idx = tid; idx < 64 * 16; idx += NT) {
            int pl = idx >> 4, kg = idx & 15;
            int pg = pt * 64 + pl;
            float4 vv = (pg < NP) ? *(const float4*)(RELb + (size_t)pg * DH + kg * 4)
                                  : make_float4(0.f, 0.f, 0.f, 0.f);
            int kc = (kg * 4) ^ ((pl & 15) << 2);   // swizzle for conflict-free col reads
            *(float4*)(&sT[pl * 64 + kc]) = vv;
        }
        __syncthreads();
        float acc0 = 0.f, acc1 = 0.f, acc2 = 0.f, acc3 = 0.f;
        for (int k0 = 0; k0 < 64; k0 += 4) {
            float4 q4 = *(const float4*)(&sQ[r * SQ_STR + k0]);
            int kc = k0 ^ (l16 << 2);  // (pl&15)==l16 for pl=l16+16c
            float4 a = *(const float4*)(&sT[(l16 +  0) * 64 + kc]);
            float4 bb = *(const float4*)(&sT[(l16 + 16) * 64 + kc]);
            float4 cc = *(const float4*)(&sT[(l16 + 32) * 64 + kc]);
            float4 dd = *(const float4*)(&sT[(l16 + 48) * 64 + kc]);
            acc0 += q4.x*a.x  + q4.y*a.y  + q4.z*a.z  + q4.w*a.w;
            acc1 += q4.x*bb.x + q4.y*bb.y + q4.z*bb.z + q4.w*bb.w;
            acc2 += q4.x*cc.x + q4.y*cc.y + q4.z*cc.z + q4.w*cc.w;
            acc3 += q4.x*dd.x + q4.y*dd.y + q4.z*dd.z + q4.w*dd.w;
        }
        int pb = pt * 64 + l16;
        if (pb      < NP) sR[r * SR_STR + pb     ] = acc0;
        if (pb + 16 < NP) sR[r * SR_STR + pb + 16] = acc1;
        if (pb + 32 < NP) sR[r * SR_STR + pb + 32] = acc2;
        if (pb + 48 < NP) sR[r * SR_STR + pb + 48] = acc3;
        __syncthreads();
    }

    // ---------- P1: reload sQ with this head's Q ----------
    for (int idx = tid; idx < TI * DH; idx += NT) {
        int rr = idx >> 6, kk = idx & 63;
        sQ[rr * SQ_STR + kk] = Qbh[(size_t)(i0 + rr) * DH + kk];
    }
    __syncthreads();

    // ---------- P2: QK^T ----------
    for (int jt = 0; jt < 16; ++jt) {
        for (int idx = tid; idx < 64 * 16; idx += NT) {
            int jl = idx >> 4, kg = idx & 15;
            float4 vv = *(const float4*)(Kbh + (size_t)(jt * 64 + jl) * DH + kg * 4);
            int kc = (kg * 4) ^ ((jl & 15) << 2);
            *(float4*)(&sT[jl * 64 + kc]) = vv;
        }
        __syncthreads();
        float acc0 = 0.f, acc1 = 0.f, acc2 = 0.f, acc3 = 0.f;
        for (int k0 = 0; k0 < 64; k0 += 4) {
            float4 q4 = *(const float4*)(&sQ[r * SQ_STR + k0]);
            int kc = k0 ^ (l16 << 2);
            float4 a = *(const float4*)(&sT[(l16 +  0) * 64 + kc]);
            float4 bb = *(const float4*)(&sT[(l16 + 16) * 64 + kc]);
            float4 cc = *(const float4*)(&sT[(l16 + 32) * 64 + kc]);
            float4 dd = *(const float4*)(&sT[(l16 + 48) * 64 + kc]);
            acc0 += q4.x*a.x  + q4.y*a.y  + q4.z*a.z  + q4.w*a.w;
            acc1 += q4.x*bb.x + q4.y*bb.y + q4.z*bb.z + q4.w*bb.w;
            acc2 += q4.x*cc.x + q4.y*cc.y + q4.z*cc.z + q4.w*cc.w;
            acc3 += q4.x*dd.x + q4.y*dd.y + q4.z*dd.z + q4.w*dd.w;
        }
        int cb = jt * 64 + l16;
        sS[r * SS_STR + cb     ] = acc0;
        sS[r * SS_STR + cb + 16] = acc1;
        sS[r * SS_STR + cb + 32] = acc2;
        sS[r * SS_STR + cb + 48] = acc3;
        __syncthreads();
    }

    // ---------- P3: gather + mask + scale (coalesced) ----------
    for (int ii = 0; ii < (TI * LSEQ) / (NT * 4); ++ii) {   // 16 iters
        int idx = ii * NT + tid;           // float4 index
        int rr  = idx >> 8;                // 256 float4 per row
        int c0  = (idx & 255) * 4;
        const int4 pm4 = *(const int4*)(PMb + (size_t)(i0 + rr) * LSEQ + c0);
        const int4 mk4 = *(const int4*)(MKb + (size_t)(i0 + rr) * LSEQ + c0);
        float4 s4 = *(float4*)(&sS[rr * SS_STR + c0]);
        const float* rrow = &sR[rr * SR_STR];
        s4.x = (mk4.x == 0) ? -1e9f : (s4.x + rrow[pm4.x]) * 0.125f;
        s4.y = (mk4.y == 0) ? -1e9f : (s4.y + rrow[pm4.y]) * 0.125f;
        s4.z = (mk4.z == 0) ? -1e9f : (s4.z + rrow[pm4.z]) * 0.125f;
        s4.w = (mk4.w == 0) ? -1e9f : (s4.w + rrow[pm4.w]) * 0.125f;
        *(float4*)(&sS[rr * SS_STR + c0]) = s4;
    }
    __syncthreads();

    // zero buckets (reuse sR)
    for (int idx = tid; idx < TI * SR_STR; idx += NT) sR[idx] = 0.f;
    __syncthreads();

    // ---------- P4: softmax per row (16 lanes / row) ----------
    {
        float m = -INFINITY;
        for (int t = 0; t < 64; ++t)
            m = fmaxf(m, sS[r * SS_STR + l16 + 16 * t]);
        #pragma unroll
        for (int o = 8; o >= 1; o >>= 1) m = fmaxf(m, __shfl_xor(m, o));
        float sum = 0.f;
        for (int t = 0; t < 64; ++t) {
            float e = __expf(sS[r * SS_STR + l16 + 16 * t] - m);
            sS[r * SS_STR + l16 + 16 * t] = e;
            sum += e;
        }
        #pragma unroll
        for (int o = 8; o >= 1; o >>= 1) sum += __shfl_xor(sum, o);
        float inv = 1.0f / sum;
        for (int t = 0; t < 64; ++t)
            sS[r * SS_STR + l16 + 16 * t] *= inv;
    }
    __syncthreads();

    // ---------- P5: write p_attn + bucket scatter ----------
    const size_t pbase = (((size_t)b * NH + h) * LSEQ + i0) * LSEQ;
    for (int ii = 0; ii < 16; ++ii) {
        int idx = ii * NT + tid;
        int rr  = idx >> 8;
        int c0  = (idx & 255) * 4;
        float4 p4 = *(const float4*)(&sS[rr * SS_STR + c0]);
        *(float4*)(OUT_P + pbase + (size_t)rr * LSEQ + c0) = p4;
        const int4 pm4 = *(const int4*)(PMb + (size_t)(i0 + rr) * LSEQ + c0);
        float* brow = &sR[rr * SR_STR];
        atomicAdd(&brow[pm4.x], p4.x);
        atomicAdd(&brow[pm4.y], p4.y);
        atomicAdd(&brow[pm4.z], p4.z);
        atomicAdd(&brow[pm4.w], p4.w);
    }
    __syncthreads();

    // ---------- P6: attn = p@V + buckets@relation ----------
    float4 acc = make_float4(0.f, 0.f, 0.f, 0.f);
    const int k0 = l16 * 4;
    for (int jt = 0; jt < 16; ++jt) {
        for (int idx = tid; idx < 64 * 16; idx += NT) {
            int jl = idx >> 4, kg = idx & 15;
            *(float4*)(&sT[jl * 64 + kg * 4]) =
                *(const float4*)(Vbh + (size_t)(jt * 64 + jl) * DH + kg * 4);
        }
        __syncthreads();
        #pragma unroll 4
        for (int j = 0; j < 64; ++j) {
            float p = sS[r * SS_STR + jt * 64 + j];
            float4 v4 = *(const float4*)(&sT[j * 64 + k0]);
            acc.x += p * v4.x; acc.y += p * v4.y; acc.z += p * v4.z; acc.w += p * v4.w;
        }
        __syncthreads();
    }
    for (int pt = 0; pt < 9; ++pt) {
        for (int idx = tid; idx < 64 * 16; idx += NT) {
            int pl = idx >> 4, kg = idx & 15;
            int pg = pt * 64 + pl;
            float4 vv = (pg < NP) ? *(const float4*)(RELb + (size_t)pg * DH + kg * 4)
                                  : make_float4(0.f, 0.f, 0.f, 0.f);
            *(float4*)(&sT[pl * 64 + kg * 4]) = vv;
        }
        __syncthreads();
        int pmax = (pt == 8) ? 1 : 64;
        #pragma unroll 4
        for (int pp = 0; pp < pmax; ++pp) {
            float a = sR[r * SR_STR + pt * 64 + pp];
            float4 v4 = *(const float4*)(&sT[pp * 64 + k0]);
            acc.x += a * v4.x; acc.y += a * v4.y; acc.z += a * v4.z; acc.w += a * v4.w;
        }
        __syncthreads();
    }
    *(float4*)(OUT_A + (((size_t)b * NH + h) * LSEQ + i0 + r) * DH + k0) = acc;
}

extern "C" void kernel_launch(void* const* d_in, const int* in_sizes, int n_in,
                              void* d_out, int out_size, void* d_ws, size_t ws_size,
                              hipStream_t stream) {
    const float* q    = (const float*)d_in[0];
    const float* k    = (const float*)d_in[1];
    const float* v    = (const float*)d_in[2];
    const float* rel  = (const float*)d_in[3];
    const int*   pm   = (const int*)d_in[4];
    const int*   mask = (const int*)d_in[5];
    float* out_a = (float*)d_out;
    float* out_p = (float*)d_out + (size_t)BSZ * NH * LSEQ * DH;

    dim3 grid(LSEQ / TI, NH, BSZ);
    raa_kernel<<<grid, NT, 0, stream>>>(q, k, v, rel, pm, mask, out_a, out_p);
}

// Round 2
// 624.239 us; speedup vs baseline: 2.5245x; 2.5245x over previous
//
#include <hip/hip_runtime.h>

// RelationAwareAttention: BS=4,H=8,L=1024,D=64,P=513, fp32 in/out.
// out = [attn_sum (B,H,L,D) | p_attn (B,H,L,L)] flat fp32.
//
// Block = 1024 threads (16 waves) handles (b, h, 16-row i-tile). Scores live
// in MFMA accumulators (wave w owns column tiles 4w..4w+3).
//   QK^T / score_r: split-bf16 (hi/lo) 3-MFMA for fp32-grade accuracy.
//   B-frags read directly from global (L2-hot); A-frags from swizzled LDS.
//   Softmax on accs with cross-wave LDS reduction; p -> global + bf16 LDS +
//   bucket scatter (LDS fp32 atomics). Then waves 0-7 do p@V, waves 8-15 do
//   buckets@relation, partials fp32-atomic into sAttn.

#define BSZ 4
#define NH 8
#define LSEQ 1024
#define DH 64
#define NP 513
#define TI 16
#define NT 1024

typedef __attribute__((ext_vector_type(8))) short bf16x8;
typedef __attribute__((ext_vector_type(4))) float f32x4;

__device__ __forceinline__ ushort f2bf(float x) {
    uint u = __float_as_uint(x);
    u += 0x7FFFu + ((u >> 16) & 1u);
    return (ushort)(u >> 16);
}
__device__ __forceinline__ float bf2f(ushort h) {
    return __uint_as_float(((uint)h) << 16);
}

__global__ __launch_bounds__(NT, 4) void raa_kernel(
    const float* __restrict__ Q, const float* __restrict__ K,
    const float* __restrict__ V, const float* __restrict__ REL,
    const int* __restrict__ PM, const int* __restrict__ MASK,
    float* __restrict__ OUT_A, float* __restrict__ OUT_P)
{
    __shared__ ushort sQh[TI * 64];     // Q hi bf16, chunk-swizzled
    __shared__ ushort sQl[TI * 64];     // Q lo bf16
    __shared__ float  sR[TI * NP];      // score_r fp32 -> reused as buckets
    __shared__ ushort sPb[TI * 1024];   // p bf16, chunk-swizzled
    __shared__ float  sAttn[TI * 64];   // output accumulator
    __shared__ float  sRed[16 * 17];    // cross-wave reduction
    __shared__ float  sFin[16];

    const int tid = threadIdx.x;
    const int w  = tid >> 6;        // wave 0..15
    const int l  = tid & 63;
    const int lg = l >> 4;          // 0..3
    const int lm = l & 15;          // 0..15

    const int it = blockIdx.x, h = blockIdx.y, b = blockIdx.z;
    const int i0 = it * TI;

    const float* Qb0  = Q + ((size_t)b * NH + 0) * LSEQ * DH;
    const float* Qbh  = Q + ((size_t)b * NH + h) * LSEQ * DH;
    const float* Kbh  = K + ((size_t)b * NH + h) * LSEQ * DH;
    const float* Vbh  = V + ((size_t)b * NH + h) * LSEQ * DH;
    const float* RELb = REL + (size_t)b * NP * DH;
    const int*   PMb  = PM  + (size_t)b * LSEQ * LSEQ;
    const int*   MKb  = MASK + (size_t)b * LSEQ * LSEQ;

    // ---- stage Q(head 0) hi/lo into swizzled LDS; zero sAttn ----
    {
        int row = tid >> 6, kk = tid & 63;
        float x = Qb0[(size_t)(i0 + row) * DH + kk];
        ushort hi = f2bf(x);
        ushort lo = f2bf(x - bf2f(hi));
        int ad = row * 64 + (((kk >> 3) ^ (row & 7)) << 3) + (kk & 7);
        sQh[ad] = hi; sQl[ad] = lo;
        sAttn[tid] = 0.f;   // TI*64 == 1024
    }
    __syncthreads();

    // ---- load Q0 A-frags into registers ----
    bf16x8 qh[2], ql[2];
    #pragma unroll
    for (int ks = 0; ks < 2; ++ks) {
        int ch = lg + 4 * ks;
        int ad = lm * 64 + ((ch ^ (lm & 7)) << 3);
        qh[ks] = *(const bf16x8*)&sQh[ad];
        ql[ks] = *(const bf16x8*)&sQl[ad];
    }
    __syncthreads();

    // ---- restage Q(head h) (frags for P0 already in regs) ----
    {
        int row = tid >> 6, kk = tid & 63;
        float x = Qbh[(size_t)(i0 + row) * DH + kk];
        ushort hi = f2bf(x);
        ushort lo = f2bf(x - bf2f(hi));
        int ad = row * 64 + (((kk >> 3) ^ (row & 7)) << 3) + (kk & 7);
        sQh[ad] = hi; sQl[ad] = lo;
    }

    // ---- P0: score_r = Q0 . REL^T  (33 coltiles over 16 waves) ----
    for (int ct = w; ct < 33; ct += 16) {
        int p0 = ct * 16;
        int prow = p0 + lm; if (prow > 512) prow = 512;
        const float* bsrc = RELb + (size_t)prow * DH + 8 * lg;
        f32x4 acc = {0.f, 0.f, 0.f, 0.f};
        #pragma unroll
        for (int ks = 0; ks < 2; ++ks) {
            float4 v0 = *(const float4*)(bsrc + ks * 32);
            float4 v1 = *(const float4*)(bsrc + ks * 32 + 4);
            float xs[8] = {v0.x, v0.y, v0.z, v0.w, v1.x, v1.y, v1.z, v1.w};
            bf16x8 bh, bl;
            #pragma unroll
            for (int e = 0; e < 8; ++e) {
                ushort hi = f2bf(xs[e]);
                bh[e] = (short)hi;
                bl[e] = (short)f2bf(xs[e] - bf2f(hi));
            }
            acc = __builtin_amdgcn_mfma_f32_16x16x32_bf16(qh[ks], bh, acc, 0, 0, 0);
            acc = __builtin_amdgcn_mfma_f32_16x16x32_bf16(ql[ks], bh, acc, 0, 0, 0);
            acc = __builtin_amdgcn_mfma_f32_16x16x32_bf16(qh[ks], bl, acc, 0, 0, 0);
        }
        int pcol = p0 + lm;
        if (pcol < NP) {
            #pragma unroll
            for (int e = 0; e < 4; ++e)
                sR[(4 * lg + e) * NP + pcol] = acc[e];
        }
    }
    __syncthreads();   // sR ready; sQ restaged

    // ---- P2: QK^T, 4 coltiles per wave, accs in registers ----
    #pragma unroll
    for (int ks = 0; ks < 2; ++ks) {
        int ch = lg + 4 * ks;
        int ad = lm * 64 + ((ch ^ (lm & 7)) << 3);
        qh[ks] = *(const bf16x8*)&sQh[ad];
        ql[ks] = *(const bf16x8*)&sQl[ad];
    }
    f32x4 acc[4];
    #pragma unroll
    for (int t = 0; t < 4; ++t) {
        int j = (4 * w + t) * 16 + lm;
        const float* bsrc = Kbh + (size_t)j * DH + 8 * lg;
        acc[t] = (f32x4){0.f, 0.f, 0.f, 0.f};
        #pragma unroll
        for (int ks = 0; ks < 2; ++ks) {
            float4 v0 = *(const float4*)(bsrc + ks * 32);
            float4 v1 = *(const float4*)(bsrc + ks * 32 + 4);
            float xs[8] = {v0.x, v0.y, v0.z, v0.w, v1.x, v1.y, v1.z, v1.w};
            bf16x8 bh, bl;
            #pragma unroll
            for (int e = 0; e < 8; ++e) {
                ushort hi = f2bf(xs[e]);
                bh[e] = (short)hi;
                bl[e] = (short)f2bf(xs[e] - bf2f(hi));
            }
            acc[t] = __builtin_amdgcn_mfma_f32_16x16x32_bf16(qh[ks], bh, acc[t], 0, 0, 0);
            acc[t] = __builtin_amdgcn_mfma_f32_16x16x32_bf16(ql[ks], bh, acc[t], 0, 0, 0);
            acc[t] = __builtin_amdgcn_mfma_f32_16x16x32_bf16(qh[ks], bl, acc[t], 0, 0, 0);
        }
    }

    // ---- P3: gather score_r[pm] + mask + scale, in-register ----
    #pragma unroll
    for (int t = 0; t < 4; ++t) {
        int col = (4 * w + t) * 16 + lm;
        #pragma unroll
        for (int e = 0; e < 4; ++e) {
            int row = 4 * lg + e;
            size_t off = (size_t)(i0 + row) * LSEQ + col;
            int pm = PMb[off];
            int mk = MKb[off];
            float g = sR[row * NP + pm];
            acc[t][e] = (mk == 0) ? -1e9f : (acc[t][e] + g) * 0.125f;
        }
    }
    __syncthreads();   // all gathers done
    for (int idx = tid; idx < TI * NP; idx += NT) sR[idx] = 0.f;  // -> buckets
    __syncthreads();

    // ---- P4: softmax (wave-local shfl + cross-wave LDS reduce) ----
    float Mr[4];
    #pragma unroll
    for (int e = 0; e < 4; ++e) {
        float m = fmaxf(fmaxf(acc[0][e], acc[1][e]), fmaxf(acc[2][e], acc[3][e]));
        #pragma unroll
        for (int o = 8; o >= 1; o >>= 1) m = fmaxf(m, __shfl_xor(m, o));
        Mr[e] = m;
    }
    if (lm == 0) {
        #pragma unroll
        for (int e = 0; e < 4; ++e) sRed[(4 * lg + e) * 17 + w] = Mr[e];
    }
    __syncthreads();
    if (w == 0 && l < 16) {
        float m = -INFINITY;
        for (int ww = 0; ww < 16; ++ww) m = fmaxf(m, sRed[l * 17 + ww]);
        sFin[l] = m;
    }
    __syncthreads();
    #pragma unroll
    for (int e = 0; e < 4; ++e) Mr[e] = sFin[4 * lg + e];

    float Sr[4];
    #pragma unroll
    for (int e = 0; e < 4; ++e) {
        float s = 0.f;
        #pragma unroll
        for (int t = 0; t < 4; ++t) {
            float v = __expf(acc[t][e] - Mr[e]);
            acc[t][e] = v;
            s += v;
        }
        #pragma unroll
        for (int o = 8; o >= 1; o >>= 1) s += __shfl_xor(s, o);
        Sr[e] = s;
    }
    if (lm == 0) {
        #pragma unroll
        for (int e = 0; e < 4; ++e) sRed[(4 * lg + e) * 17 + w] = Sr[e];
    }
    __syncthreads();
    if (w == 0 && l < 16) {
        float s = 0.f;
        for (int ww = 0; ww < 16; ++ww) s += sRed[l * 17 + ww];
        sFin[l] = s;
    }
    __syncthreads();

    // ---- P5: finalize p; write p_attn, p->bf16 LDS, bucket scatter ----
    float inv[4];
    #pragma unroll
    for (int e = 0; e < 4; ++e) inv[e] = 1.0f / sFin[4 * lg + e];

    const size_t pbase = (((size_t)b * NH + h) * LSEQ + i0) * LSEQ;
    #pragma unroll
    for (int t = 0; t < 4; ++t) {
        int col = (4 * w + t) * 16 + lm;
        #pragma unroll
        for (int e = 0; e < 4; ++e) {
            int row = 4 * lg + e;
            float p = acc[t][e] * inv[e];
            OUT_P[pbase + (size_t)row * LSEQ + col] = p;
            int ad = row * 1024 + (((col >> 3) ^ (row & 7)) << 3) + (col & 7);
            sPb[ad] = f2bf(p);
            int pm = PMb[(size_t)(i0 + row) * LSEQ + col];   // L1/L2-hot reload
            atomicAdd(&sR[row * NP + pm], p);
        }
    }
    __syncthreads();   // sPb + buckets ready

    // ---- P6: waves 0-7: p@V ; waves 8-15: buckets@REL ----
    if (w < 8) {
        int ct = w >> 1, jh = w & 1;
        int d = ct * 16 + lm;
        f32x4 pa = {0.f, 0.f, 0.f, 0.f};
        for (int ks = 0; ks < 16; ++ks) {
            int j0 = jh * 512 + ks * 32;
            int ch = (j0 >> 3) + lg;
            bf16x8 a = *(const bf16x8*)&sPb[lm * 1024 + ((ch ^ (lm & 7)) << 3)];
            const float* vs = Vbh + (size_t)(j0 + 8 * lg) * DH + d;
            bf16x8 bb;
            #pragma unroll
            for (int e = 0; e < 8; ++e) bb[e] = (short)f2bf(vs[(size_t)e * DH]);
            pa = __builtin_amdgcn_mfma_f32_16x16x32_bf16(a, bb, pa, 0, 0, 0);
        }
        #pragma unroll
        for (int e = 0; e < 4; ++e)
            atomicAdd(&sAttn[(4 * lg + e) * 64 + d], pa[e]);
    } else {
        int ct = (w - 8) >> 1, ph = w & 1;
        int d = ct * 16 + lm;
        int nks = ph ? 9 : 8;
        f32x4 pa = {0.f, 0.f, 0.f, 0.f};
        for (int ks = 0; ks < nks; ++ks) {
            int p0 = ph * 256 + ks * 32 + 8 * lg;
            bf16x8 a, bb;
            #pragma unroll
            for (int e = 0; e < 8; ++e) {
                int pp = p0 + e;
                float av = (pp < NP) ? sR[lm * NP + pp] : 0.f;
                a[e] = (short)f2bf(av);
                int pc = (pp < NP) ? pp : (NP - 1);
                bb[e] = (short)f2bf(RELb[(size_t)pc * DH + d]);
            }
            pa = __builtin_amdgcn_mfma_f32_16x16x32_bf16(a, bb, pa, 0, 0, 0);
        }
        #pragma unroll
        for (int e = 0; e < 4; ++e)
            atomicAdd(&sAttn[(4 * lg + e) * 64 + d], pa[e]);
    }
    __syncthreads();

    // ---- write attn_sum ----
    {
        int row = tid >> 6, col = tid & 63;
        OUT_A[(((size_t)b * NH + h) * LSEQ + i0 + row) * DH + col] =
            sAttn[row * 64 + col];
    }
}

extern "C" void kernel_launch(void* const* d_in, const int* in_sizes, int n_in,
                              void* d_out, int out_size, void* d_ws, size_t ws_size,
                              hipStream_t stream) {
    const float* q    = (const float*)d_in[0];
    const float* k    = (const float*)d_in[1];
    const float* v    = (const float*)d_in[2];
    const float* rel  = (const float*)d_in[3];
    const int*   pm   = (const int*)d_in[4];
    const int*   mask = (const int*)d_in[5];
    float* out_a = (float*)d_out;
    float* out_p = (float*)d_out + (size_t)BSZ * NH * LSEQ * DH;

    dim3 grid(LSEQ / TI, NH, BSZ);
    raa_kernel<<<grid, NT, 0, stream>>>(q, k, v, rel, pm, mask, out_a, out_p);
}

// Round 3
// 585.844 us; speedup vs baseline: 2.6899x; 1.0655x over previous
//
#include <hip/hip_runtime.h>

// RelationAwareAttention: BS=4,H=8,L=1024,D=64,P=513, fp32 in/out.
// out = [attn_sum (B,H,L,D) | p_attn (B,H,L,L)] flat fp32.
//
// R3: prep pass converts operands once into d_ws:
//   Qh/Ql, Kh/Kl  : bf16 hi/lo planes, row-major [*,64]   (split-bf16 QK^T)
//   Vt            : bf16 V transposed  [b,h,64,1024]
//   RELh/RELl     : bf16 hi/lo [b,513,64]
//   Rt            : bf16 REL transposed+padded [b,64,544]
// Main kernel then feeds MFMA purely from contiguous 16B loads.
// Falls back to the self-contained R2 kernel if ws_size is too small.

#define BSZ 4
#define NH 8
#define LSEQ 1024
#define DH 64
#define NP 513
#define TI 16
#define NT 1024
#define SRX 545            // LDS X row stride (floats) -- 545%32=1 spreads banks
#define RTC 544            // Rt padded cols

#define NQE (BSZ*NH*LSEQ*DH)   // 2097152 elems per Q/K plane
#define NRE (BSZ*NP*DH)        // 131328
#define NRT (BSZ*DH*RTC)       // 139264
#define OFF_QH 0
#define OFF_QL (NQE)
#define OFF_KH (2*NQE)
#define OFF_KL (3*NQE)
#define OFF_VT (4*NQE)
#define OFF_RH (5*NQE)
#define OFF_RL (5*NQE + NRE)
#define OFF_RT (5*NQE + 2*NRE)
#define WS_NEED ((size_t)(5*(size_t)NQE + 2*(size_t)NRE + (size_t)NRT) * 2)

typedef __attribute__((ext_vector_type(8))) short bf16x8;
typedef __attribute__((ext_vector_type(4))) float f32x4;
typedef __attribute__((ext_vector_type(4))) ushort u16x4;

__device__ __forceinline__ ushort f2bf(float x) {
    uint u = __float_as_uint(x);
    u += 0x7FFFu + ((u >> 16) & 1u);
    return (ushort)(u >> 16);
}
__device__ __forceinline__ float bf2f(ushort h) {
    return __uint_as_float(((uint)h) << 16);
}

// ---------------- prep kernels ----------------

__global__ void prep_qk(const float* __restrict__ Q, const float* __restrict__ K,
                        ushort* __restrict__ ws) {
    const int n4 = NQE / 4;
    for (int i = blockIdx.x * blockDim.x + threadIdx.x; i < 2 * n4;
         i += gridDim.x * blockDim.x) {
        int isK = i >= n4;
        int base = i - isK * n4;
        float4 v = ((const float4*)(isK ? K : Q))[base];
        float xs[4] = {v.x, v.y, v.z, v.w};
        u16x4 hh, ll;
        #pragma unroll
        for (int e = 0; e < 4; ++e) {
            ushort hi = f2bf(xs[e]);
            hh[e] = hi;
            ll[e] = f2bf(xs[e] - bf2f(hi));
        }
        *(u16x4*)(ws + (isK ? OFF_KH : OFF_QH) + (size_t)base * 4) = hh;
        *(u16x4*)(ws + (isK ? OFF_KL : OFF_QL) + (size_t)base * 4) = ll;
    }
}

__global__ void prep_rel(const float* __restrict__ REL, ushort* __restrict__ ws) {
    const int tot = NRE + NRT;
    for (int i = blockIdx.x * blockDim.x + threadIdx.x; i < tot;
         i += gridDim.x * blockDim.x) {
        if (i < NRE) {
            float x = REL[i];
            ushort hi = f2bf(x);
            ws[OFF_RH + i] = hi;
            ws[OFF_RL + i] = f2bf(x - bf2f(hi));
        } else {
            int j = i - NRE;
            int b = j / (DH * RTC);
            int r = j - b * (DH * RTC);
            int d = r / RTC;
            int p = r - d * RTC;
            float x = (p < NP) ? REL[((size_t)b * NP + p) * DH + d] : 0.f;
            ws[OFF_RT + j] = f2bf(x);
        }
    }
}

__global__ void prep_vt(const float* __restrict__ V, ushort* __restrict__ ws) {
    for (int i = blockIdx.x * blockDim.x + threadIdx.x; i < NQE;
         i += gridDim.x * blockDim.x) {
        int bh = i >> 16;          // DH*LSEQ = 65536
        int r  = i & 65535;
        int d  = r >> 10;
        int j  = r & 1023;
        ws[OFF_VT + (size_t)i] = f2bf(V[((size_t)bh << 16) + (j << 6) + d]);
    }
}

// ---------------- main kernel ----------------

__global__ __launch_bounds__(NT, 4) void raa_main(
    const ushort* __restrict__ ws,
    const int* __restrict__ PM, const int* __restrict__ MASK,
    float* __restrict__ OUT_A, float* __restrict__ OUT_P)
{
    __shared__ float  X[TI * SRX];      // score_r fp32 -> buckets (34.9 KB)
    __shared__ ushort sPb[TI * 1024];   // p bf16, chunk-swizzled (32.8 KB)
    __shared__ float  sAttn[TI * DH];   // 4 KB
    __shared__ float  sRed[16 * 17];
    __shared__ float  sFin[16];

    const int tid = threadIdx.x;
    const int w  = tid >> 6;
    const int l  = tid & 63;
    const int lg = l >> 4;
    const int lm = l & 15;

    const int it = blockIdx.x, h = blockIdx.y, b = blockIdx.z;
    const int i0 = it * TI;
    const int bh = b * NH + h;

    const ushort* Qh  = ws + OFF_QH + (size_t)bh * LSEQ * DH;
    const ushort* Ql  = ws + OFF_QL + (size_t)bh * LSEQ * DH;
    const ushort* Q0h = ws + OFF_QH + (size_t)b * NH * LSEQ * DH;
    const ushort* Q0l = ws + OFF_QL + (size_t)b * NH * LSEQ * DH;
    const ushort* Kh  = ws + OFF_KH + (size_t)bh * LSEQ * DH;
    const ushort* Kl  = ws + OFF_KL + (size_t)bh * LSEQ * DH;
    const ushort* Vt  = ws + OFF_VT + (size_t)bh * DH * LSEQ;
    const ushort* Rh  = ws + OFF_RH + (size_t)b * NP * DH;
    const ushort* Rl  = ws + OFF_RL + (size_t)b * NP * DH;
    const ushort* Rt  = ws + OFF_RT + (size_t)b * DH * RTC;
    const int* PMb = PM + (size_t)b * LSEQ * LSEQ;
    const int* MKb = MASK + (size_t)b * LSEQ * LSEQ;

    sAttn[tid] = 0.f;   // NT == TI*DH

    // ---- A-fragments straight from global (contiguous 16B) ----
    bf16x8 q0h[2], q0l[2], qhh[2], qhl[2];
    #pragma unroll
    for (int ks = 0; ks < 2; ++ks) {
        size_t ao = (size_t)(i0 + lm) * DH + ks * 32 + lg * 8;
        q0h[ks] = *(const bf16x8*)(Q0h + ao);
        q0l[ks] = *(const bf16x8*)(Q0l + ao);
        qhh[ks] = *(const bf16x8*)(Qh + ao);
        qhl[ks] = *(const bf16x8*)(Ql + ao);
    }

    // ---- prefetch PM/MASK into regs (latency hides under MFMA) ----
    int pmr[16], mkr[16];
    #pragma unroll
    for (int t = 0; t < 4; ++t) {
        #pragma unroll
        for (int e = 0; e < 4; ++e) {
            int col = (4 * w + t) * 16 + lm;
            int row = 4 * lg + e;
            size_t off = (size_t)(i0 + row) * LSEQ + col;
            pmr[t * 4 + e] = PMb[off];
            mkr[t * 4 + e] = MKb[off];
        }
    }

    // ---- P0: score_r = Q0 . REL^T ----
    for (int ct = w; ct < 33; ct += 16) {
        int p0 = ct * 16;
        int prow = p0 + lm; if (prow > 512) prow = 512;
        f32x4 a0 = {0.f, 0.f, 0.f, 0.f};
        #pragma unroll
        for (int ks = 0; ks < 2; ++ks) {
            size_t bo = (size_t)prow * DH + ks * 32 + lg * 8;
            bf16x8 bh8 = *(const bf16x8*)(Rh + bo);
            bf16x8 bl8 = *(const bf16x8*)(Rl + bo);
            a0 = __builtin_amdgcn_mfma_f32_16x16x32_bf16(q0h[ks], bh8, a0, 0, 0, 0);
            a0 = __builtin_amdgcn_mfma_f32_16x16x32_bf16(q0l[ks], bh8, a0, 0, 0, 0);
            a0 = __builtin_amdgcn_mfma_f32_16x16x32_bf16(q0h[ks], bl8, a0, 0, 0, 0);
        }
        if (p0 + lm < NP) {
            #pragma unroll
            for (int e = 0; e < 4; ++e)
                X[(4 * lg + e) * SRX + p0 + lm] = a0[e];
        }
    }

    // ---- P2: QK^T (no LDS involved) ----
    f32x4 acc[4];
    #pragma unroll
    for (int t = 0; t < 4; ++t) {
        int j0 = (4 * w + t) * 16;
        acc[t] = (f32x4){0.f, 0.f, 0.f, 0.f};
        #pragma unroll
        for (int ks = 0; ks < 2; ++ks) {
            size_t bo = (size_t)(j0 + lm) * DH + ks * 32 + lg * 8;
            bf16x8 kh8 = *(const bf16x8*)(Kh + bo);
            bf16x8 kl8 = *(const bf16x8*)(Kl + bo);
            acc[t] = __builtin_amdgcn_mfma_f32_16x16x32_bf16(qhh[ks], kh8, acc[t], 0, 0, 0);
            acc[t] = __builtin_amdgcn_mfma_f32_16x16x32_bf16(qhl[ks], kh8, acc[t], 0, 0, 0);
            acc[t] = __builtin_amdgcn_mfma_f32_16x16x32_bf16(qhh[ks], kl8, acc[t], 0, 0, 0);
        }
    }
    __syncthreads();   // X (score_r) complete

    // ---- P3: gather + mask + scale ----
    #pragma unroll
    for (int t = 0; t < 4; ++t) {
        #pragma unroll
        for (int e = 0; e < 4; ++e) {
            int row = 4 * lg + e;
            float g = X[row * SRX + pmr[t * 4 + e]];
            acc[t][e] = (mkr[t * 4 + e] == 0) ? -1e9f : (acc[t][e] + g) * 0.125f;
        }
    }
    __syncthreads();   // done reading score_r
    for (int idx = tid; idx < TI * SRX; idx += NT) X[idx] = 0.f;  // -> buckets
    __syncthreads();

    // ---- P4: softmax ----
    float Mr[4];
    #pragma unroll
    for (int e = 0; e < 4; ++e) {
        float m = fmaxf(fmaxf(acc[0][e], acc[1][e]), fmaxf(acc[2][e], acc[3][e]));
        #pragma unroll
        for (int o = 8; o >= 1; o >>= 1) m = fmaxf(m, __shfl_xor(m, o));
        Mr[e] = m;
    }
    if (lm == 0) {
        #pragma unroll
        for (int e = 0; e < 4; ++e) sRed[(4 * lg + e) * 17 + w] = Mr[e];
    }
    __syncthreads();
    if (w == 0 && l < 16) {
        float m = -INFINITY;
        for (int ww = 0; ww < 16; ++ww) m = fmaxf(m, sRed[l * 17 + ww]);
        sFin[l] = m;
    }
    __syncthreads();
    #pragma unroll
    for (int e = 0; e < 4; ++e) Mr[e] = sFin[4 * lg + e];

    float Sr[4];
    #pragma unroll
    for (int e = 0; e < 4; ++e) {
        float s = 0.f;
        #pragma unroll
        for (int t = 0; t < 4; ++t) {
            float v = __expf(acc[t][e] - Mr[e]);
            acc[t][e] = v;
            s += v;
        }
        #pragma unroll
        for (int o = 8; o >= 1; o >>= 1) s += __shfl_xor(s, o);
        Sr[e] = s;
    }
    if (lm == 0) {
        #pragma unroll
        for (int e = 0; e < 4; ++e) sRed[(4 * lg + e) * 17 + w] = Sr[e];
    }
    __syncthreads();
    if (w == 0 && l < 16) {
        float s = 0.f;
        for (int ww = 0; ww < 16; ++ww) s += sRed[l * 17 + ww];
        sFin[l] = s;
    }
    __syncthreads();

    // ---- P5: finalize p; write p_attn + bf16 LDS + bucket scatter ----
    float inv[4];
    #pragma unroll
    for (int e = 0; e < 4; ++e) inv[e] = 1.0f / sFin[4 * lg + e];

    const size_t pbase = (((size_t)bh) * LSEQ + i0) * LSEQ;
    #pragma unroll
    for (int t = 0; t < 4; ++t) {
        int col = (4 * w + t) * 16 + lm;
        #pragma unroll
        for (int e = 0; e < 4; ++e) {
            int row = 4 * lg + e;
            float p = acc[t][e] * inv[e];
            OUT_P[pbase + (size_t)row * LSEQ + col] = p;
            sPb[row * 1024 + (((col >> 3) ^ (row & 7)) << 3) + (col & 7)] = f2bf(p);
            atomicAdd(&X[row * SRX + pmr[t * 4 + e]], p);
        }
    }
    __syncthreads();

    // ---- P6: waves 0-7: p@V (B from Vt); waves 8-15: buckets@REL (B from Rt) ----
    if (w < 8) {
        int ct = w >> 1, jh = w & 1;
        int d0 = ct * 16;
        f32x4 pa = {0.f, 0.f, 0.f, 0.f};
        #pragma unroll 4
        for (int ks = 0; ks < 16; ++ks) {
            int j0 = jh * 512 + ks * 32;
            int ch = (j0 >> 3) + lg;
            bf16x8 a = *(const bf16x8*)&sPb[lm * 1024 + ((ch ^ (lm & 7)) << 3)];
            bf16x8 bb = *(const bf16x8*)(Vt + (size_t)(d0 + lm) * LSEQ + j0 + lg * 8);
            pa = __builtin_amdgcn_mfma_f32_16x16x32_bf16(a, bb, pa, 0, 0, 0);
        }
        #pragma unroll
        for (int e = 0; e < 4; ++e)
            atomicAdd(&sAttn[(4 * lg + e) * DH + d0 + lm], pa[e]);
    } else {
        int ct = (w - 8) >> 1, ph = w & 1;
        int d0 = ct * 16;
        int nks = ph ? 8 : 9;
        int pb0 = ph ? 288 : 0;
        f32x4 pa = {0.f, 0.f, 0.f, 0.f};
        for (int ks = 0; ks < nks; ++ks) {
            int p0 = pb0 + ks * 32;
            bf16x8 a;
            #pragma unroll
            for (int e = 0; e < 8; ++e)
                a[e] = (short)f2bf(X[lm * SRX + p0 + lg * 8 + e]);
            bf16x8 bb = *(const bf16x8*)(Rt + (size_t)(d0 + lm) * RTC + p0 + lg * 8);
            pa = __builtin_amdgcn_mfma_f32_16x16x32_bf16(a, bb, pa, 0, 0, 0);
        }
        #pragma unroll
        for (int e = 0; e < 4; ++e)
            atomicAdd(&sAttn[(4 * lg + e) * DH + d0 + lm], pa[e]);
    }
    __syncthreads();

    OUT_A[(((size_t)bh) * LSEQ + i0 + (tid >> 6)) * DH + (tid & 63)] = sAttn[tid];
}

// ---------------- fallback (R2 kernel, self-contained) ----------------

__global__ __launch_bounds__(NT, 4) void raa_fallback(
    const float* __restrict__ Q, const float* __restrict__ K,
    const float* __restrict__ V, const float* __restrict__ REL,
    const int* __restrict__ PM, const int* __restrict__ MASK,
    float* __restrict__ OUT_A, float* __restrict__ OUT_P)
{
    __shared__ ushort sQh[TI * 64];
    __shared__ ushort sQl[TI * 64];
    __shared__ float  sR[TI * NP];
    __shared__ ushort sPb[TI * 1024];
    __shared__ float  sAttn[TI * 64];
    __shared__ float  sRed[16 * 17];
    __shared__ float  sFin[16];

    const int tid = threadIdx.x;
    const int w  = tid >> 6;
    const int l  = tid & 63;
    const int lg = l >> 4;
    const int lm = l & 15;

    const int it = blockIdx.x, h = blockIdx.y, b = blockIdx.z;
    const int i0 = it * TI;

    const float* Qb0  = Q + ((size_t)b * NH + 0) * LSEQ * DH;
    const float* Qbh  = Q + ((size_t)b * NH + h) * LSEQ * DH;
    const float* Kbh  = K + ((size_t)b * NH + h) * LSEQ * DH;
    const float* Vbh  = V + ((size_t)b * NH + h) * LSEQ * DH;
    const float* RELb = REL + (size_t)b * NP * DH;
    const int*   PMb  = PM  + (size_t)b * LSEQ * LSEQ;
    const int*   MKb  = MASK + (size_t)b * LSEQ * LSEQ;

    {
        int row = tid >> 6, kk = tid & 63;
        float x = Qb0[(size_t)(i0 + row) * DH + kk];
        ushort hi = f2bf(x);
        ushort lo = f2bf(x - bf2f(hi));
        int ad = row * 64 + (((kk >> 3) ^ (row & 7)) << 3) + (kk & 7);
        sQh[ad] = hi; sQl[ad] = lo;
        sAttn[tid] = 0.f;
    }
    __syncthreads();

    bf16x8 qh[2], ql[2];
    #pragma unroll
    for (int ks = 0; ks < 2; ++ks) {
        int ch = lg + 4 * ks;
        int ad = lm * 64 + ((ch ^ (lm & 7)) << 3);
        qh[ks] = *(const bf16x8*)&sQh[ad];
        ql[ks] = *(const bf16x8*)&sQl[ad];
    }
    __syncthreads();

    {
        int row = tid >> 6, kk = tid & 63;
        float x = Qbh[(size_t)(i0 + row) * DH + kk];
        ushort hi = f2bf(x);
        ushort lo = f2bf(x - bf2f(hi));
        int ad = row * 64 + (((kk >> 3) ^ (row & 7)) << 3) + (kk & 7);
        sQh[ad] = hi; sQl[ad] = lo;
    }

    for (int ct = w; ct < 33; ct += 16) {
        int p0 = ct * 16;
        int prow = p0 + lm; if (prow > 512) prow = 512;
        const float* bsrc = RELb + (size_t)prow * DH + 8 * lg;
        f32x4 acc = {0.f, 0.f, 0.f, 0.f};
        #pragma unroll
        for (int ks = 0; ks < 2; ++ks) {
            float4 v0 = *(const float4*)(bsrc + ks * 32);
            float4 v1 = *(const float4*)(bsrc + ks * 32 + 4);
            float xs[8] = {v0.x, v0.y, v0.z, v0.w, v1.x, v1.y, v1.z, v1.w};
            bf16x8 bh, bl;
            #pragma unroll
            for (int e = 0; e < 8; ++e) {
                ushort hi = f2bf(xs[e]);
                bh[e] = (short)hi;
                bl[e] = (short)f2bf(xs[e] - bf2f(hi));
            }
            acc = __builtin_amdgcn_mfma_f32_16x16x32_bf16(qh[ks], bh, acc, 0, 0, 0);
            acc = __builtin_amdgcn_mfma_f32_16x16x32_bf16(ql[ks], bh, acc, 0, 0, 0);
            acc = __builtin_amdgcn_mfma_f32_16x16x32_bf16(qh[ks], bl, acc, 0, 0, 0);
        }
        int pcol = p0 + lm;
        if (pcol < NP) {
            #pragma unroll
            for (int e = 0; e < 4; ++e)
                sR[(4 * lg + e) * NP + pcol] = acc[e];
        }
    }
    __syncthreads();

    {
        int ad0;
        #pragma unroll
        for (int ks = 0; ks < 2; ++ks) {
            int ch = lg + 4 * ks;
            ad0 = lm * 64 + ((ch ^ (lm & 7)) << 3);
            qh[ks] = *(const bf16x8*)&sQh[ad0];
            ql[ks] = *(const bf16x8*)&sQl[ad0];
        }
    }
    f32x4 acc[4];
    #pragma unroll
    for (int t = 0; t < 4; ++t) {
        int j = (4 * w + t) * 16 + lm;
        const float* bsrc = Kbh + (size_t)j * DH + 8 * lg;
        acc[t] = (f32x4){0.f, 0.f, 0.f, 0.f};
        #pragma unroll
        for (int ks = 0; ks < 2; ++ks) {
            float4 v0 = *(const float4*)(bsrc + ks * 32);
            float4 v1 = *(const float4*)(bsrc + ks * 32 + 4);
            float xs[8] = {v0.x, v0.y, v0.z, v0.w, v1.x, v1.y, v1.z, v1.w};
            bf16x8 bh, bl;
            #pragma unroll
            for (int e = 0; e < 8; ++e) {
                ushort hi = f2bf(xs[e]);
                bh[e] = (short)hi;
                bl[e] = (short)f2bf(xs[e] - bf2f(hi));
            }
            acc[t] = __builtin_amdgcn_mfma_f32_16x16x32_bf16(qh[ks], bh, acc[t], 0, 0, 0);
            acc[t] = __builtin_amdgcn_mfma_f32_16x16x32_bf16(ql[ks], bh, acc[t], 0, 0, 0);
            acc[t] = __builtin_amdgcn_mfma_f32_16x16x32_bf16(qh[ks], bl, acc[t], 0, 0, 0);
        }
    }

    #pragma unroll
    for (int t = 0; t < 4; ++t) {
        int col = (4 * w + t) * 16 + lm;
        #pragma unroll
        for (int e = 0; e < 4; ++e) {
            int row = 4 * lg + e;
            size_t off = (size_t)(i0 + row) * LSEQ + col;
            int pm = PMb[off];
            int mk = MKb[off];
            float g = sR[row * NP + pm];
            acc[t][e] = (mk == 0) ? -1e9f : (acc[t][e] + g) * 0.125f;
        }
    }
    __syncthreads();
    for (int idx = tid; idx < TI * NP; idx += NT) sR[idx] = 0.f;
    __syncthreads();

    float Mr[4];
    #pragma unroll
    for (int e = 0; e < 4; ++e) {
        float m = fmaxf(fmaxf(acc[0][e], acc[1][e]), fmaxf(acc[2][e], acc[3][e]));
        #pragma unroll
        for (int o = 8; o >= 1; o >>= 1) m = fmaxf(m, __shfl_xor(m, o));
        Mr[e] = m;
    }
    if (lm == 0) {
        #pragma unroll
        for (int e = 0; e < 4; ++e) sRed[(4 * lg + e) * 17 + w] = Mr[e];
    }
    __syncthreads();
    if (w == 0 && l < 16) {
        float m = -INFINITY;
        for (int ww = 0; ww < 16; ++ww) m = fmaxf(m, sRed[l * 17 + ww]);
        sFin[l] = m;
    }
    __syncthreads();
    #pragma unroll
    for (int e = 0; e < 4; ++e) Mr[e] = sFin[4 * lg + e];

    float Sr[4];
    #pragma unroll
    for (int e = 0; e < 4; ++e) {
        float s = 0.f;
        #pragma unroll
        for (int t = 0; t < 4; ++t) {
            float v = __expf(acc[t][e] - Mr[e]);
            acc[t][e] = v;
            s += v;
        }
        #pragma unroll
        for (int o = 8; o >= 1; o >>= 1) s += __shfl_xor(s, o);
        Sr[e] = s;
    }
    if (lm == 0) {
        #pragma unroll
        for (int e = 0; e < 4; ++e) sRed[(4 * lg + e) * 17 + w] = Sr[e];
    }
    __syncthreads();
    if (w == 0 && l < 16) {
        float s = 0.f;
        for (int ww = 0; ww < 16; ++ww) s += sRed[l * 17 + ww];
        sFin[l] = s;
    }
    __syncthreads();

    float inv[4];
    #pragma unroll
    for (int e = 0; e < 4; ++e) inv[e] = 1.0f / sFin[4 * lg + e];

    const size_t pbase = (((size_t)b * NH + h) * LSEQ + i0) * LSEQ;
    #pragma unroll
    for (int t = 0; t < 4; ++t) {
        int col = (4 * w + t) * 16 + lm;
        #pragma unroll
        for (int e = 0; e < 4; ++e) {
            int row = 4 * lg + e;
            float p = acc[t][e] * inv[e];
            OUT_P[pbase + (size_t)row * LSEQ + col] = p;
            int ad = row * 1024 + (((col >> 3) ^ (row & 7)) << 3) + (col & 7);
            sPb[ad] = f2bf(p);
            int pm = PMb[(size_t)(i0 + row) * LSEQ + col];
            atomicAdd(&sR[row * NP + pm], p);
        }
    }
    __syncthreads();

    if (w < 8) {
        int ct = w >> 1, jh = w & 1;
        int d = ct * 16 + lm;
        f32x4 pa = {0.f, 0.f, 0.f, 0.f};
        for (int ks = 0; ks < 16; ++ks) {
            int j0 = jh * 512 + ks * 32;
            int ch = (j0 >> 3) + lg;
            bf16x8 a = *(const bf16x8*)&sPb[lm * 1024 + ((ch ^ (lm & 7)) << 3)];
            const float* vs = Vbh + (size_t)(j0 + 8 * lg) * DH + d;
            bf16x8 bb;
            #pragma unroll
            for (int e = 0; e < 8; ++e) bb[e] = (short)f2bf(vs[(size_t)e * DH]);
            pa = __builtin_amdgcn_mfma_f32_16x16x32_bf16(a, bb, pa, 0, 0, 0);
        }
        #pragma unroll
        for (int e = 0; e < 4; ++e)
            atomicAdd(&sAttn[(4 * lg + e) * 64 + d], pa[e]);
    } else {
        int ct = (w - 8) >> 1, ph = w & 1;
        int d = ct * 16 + lm;
        int nks = ph ? 9 : 8;
        f32x4 pa = {0.f, 0.f, 0.f, 0.f};
        for (int ks = 0; ks < nks; ++ks) {
            int p0 = ph * 256 + ks * 32 + 8 * lg;
            bf16x8 a, bb;
            #pragma unroll
            for (int e = 0; e < 8; ++e) {
                int pp = p0 + e;
                float av = (pp < NP) ? sR[lm * NP + pp] : 0.f;
                a[e] = (short)f2bf(av);
                int pc = (pp < NP) ? pp : (NP - 1);
                bb[e] = (short)f2bf(RELb[(size_t)pc * DH + d]);
            }
            pa = __builtin_amdgcn_mfma_f32_16x16x32_bf16(a, bb, pa, 0, 0, 0);
        }
        #pragma unroll
        for (int e = 0; e < 4; ++e)
            atomicAdd(&sAttn[(4 * lg + e) * 64 + d], pa[e]);
    }
    __syncthreads();

    {
        int row = tid >> 6, col = tid & 63;
        OUT_A[(((size_t)b * NH + h) * LSEQ + i0 + row) * DH + col] =
            sAttn[row * 64 + col];
    }
}

extern "C" void kernel_launch(void* const* d_in, const int* in_sizes, int n_in,
                              void* d_out, int out_size, void* d_ws, size_t ws_size,
                              hipStream_t stream) {
    const float* q    = (const float*)d_in[0];
    const float* k    = (const float*)d_in[1];
    const float* v    = (const float*)d_in[2];
    const float* rel  = (const float*)d_in[3];
    const int*   pm   = (const int*)d_in[4];
    const int*   mask = (const int*)d_in[5];
    float* out_a = (float*)d_out;
    float* out_p = (float*)d_out + (size_t)BSZ * NH * LSEQ * DH;

    dim3 grid(LSEQ / TI, NH, BSZ);
    if (ws_size >= WS_NEED && d_ws != nullptr) {
        ushort* ws = (ushort*)d_ws;
        prep_qk<<<2048, 256, 0, stream>>>(q, k, ws);
        prep_rel<<<512, 256, 0, stream>>>(rel, ws);
        prep_vt<<<2048, 256, 0, stream>>>(v, ws);
        raa_main<<<grid, NT, 0, stream>>>((const ushort*)ws, pm, mask, out_a, out_p);
    } else {
        raa_fallback<<<grid, NT, 0, stream>>>(q, k, v, rel, pm, mask, out_a, out_p);
    }
}

// Round 4
// 569.104 us; speedup vs baseline: 2.7691x; 1.0294x over previous
//
#include <hip/hip_runtime.h>

// RelationAwareAttention: BS=4,H=8,L=1024,D=64,P=513, fp32 in/out.
// out = [attn_sum (B,H,L,D) | p_attn (B,H,L,L)] flat fp32.
//
// R4: prep pass converts operands once into d_ws:
//   Qh/Ql, Kh/Kl : bf16 hi/lo planes, row-major [*,64] (split-bf16 QK^T)
//   Vt           : bf16 V transposed [b,h,64,1024]      (LDS tile transpose)
//   Rt           : bf16 REL transposed+padded [b,64,544]
//   SR           : bf16 score_r table [b,1024,513]      (computed ONCE, not 8x)
// Main kernel: front-loaded PM/MASK/gather/K loads overlapped under MFMA,
// 1-barrier softmax, vectorized p_attn store. Fallback if ws too small.

#define BSZ 4
#define NH 8
#define LSEQ 1024
#define DH 64
#define NP 513
#define TI 16
#define NT 1024
#define SRX 545            // LDS bucket row stride (floats), 545%32=1
#define RTC 544            // Rt padded cols

#define NQE (BSZ*NH*LSEQ*DH)   // 2097152 elems per plane
#define NRT (BSZ*DH*RTC)       // 139264
#define NSR (BSZ*LSEQ*NP)      // 2101248
#define OFF_QH 0
#define OFF_QL (NQE)
#define OFF_KH (2*NQE)
#define OFF_KL (3*NQE)
#define OFF_VT (4*NQE)
#define OFF_RT (5*NQE)
#define OFF_SR (5*NQE + NRT)
#define WS_NEED ((size_t)(5*(size_t)NQE + (size_t)NRT + (size_t)NSR) * 2)

typedef __attribute__((ext_vector_type(8))) short bf16x8;
typedef __attribute__((ext_vector_type(4))) float f32x4;
typedef __attribute__((ext_vector_type(4))) ushort u16x4;

__device__ __forceinline__ ushort f2bf(float x) {
    uint u = __float_as_uint(x);
    u += 0x7FFFu + ((u >> 16) & 1u);
    return (ushort)(u >> 16);
}
__device__ __forceinline__ float bf2f(ushort h) {
    return __uint_as_float(((uint)h) << 16);
}

// ---------------- prep kernels ----------------

__global__ void prep_qk(const float* __restrict__ Q, const float* __restrict__ K,
                        ushort* __restrict__ ws) {
    const int n4 = NQE / 4;
    for (int i = blockIdx.x * blockDim.x + threadIdx.x; i < 2 * n4;
         i += gridDim.x * blockDim.x) {
        int isK = i >= n4;
        int base = i - isK * n4;
        float4 v = ((const float4*)(isK ? K : Q))[base];
        float xs[4] = {v.x, v.y, v.z, v.w};
        u16x4 hh, ll;
        #pragma unroll
        for (int e = 0; e < 4; ++e) {
            ushort hi = f2bf(xs[e]);
            hh[e] = hi;
            ll[e] = f2bf(xs[e] - bf2f(hi));
        }
        *(u16x4*)(ws + (isK ? OFF_KH : OFF_QH) + (size_t)base * 4) = hh;
        *(u16x4*)(ws + (isK ? OFF_KL : OFF_QL) + (size_t)base * 4) = ll;
    }
}

__global__ void prep_rt(const float* __restrict__ REL, ushort* __restrict__ ws) {
    for (int i = blockIdx.x * blockDim.x + threadIdx.x; i < NRT;
         i += gridDim.x * blockDim.x) {
        int b = i / (DH * RTC);
        int r = i - b * (DH * RTC);
        int d = r / RTC;
        int p = r - d * RTC;
        float x = (p < NP) ? REL[((size_t)b * NP + p) * DH + d] : 0.f;
        ws[OFF_RT + i] = f2bf(x);
    }
}

// V transpose via LDS tile (coalesced in AND out)
__global__ __launch_bounds__(256) void prep_vt(const float* __restrict__ V,
                                               ushort* __restrict__ ws) {
    __shared__ float sT[64 * 65];
    const int bh = blockIdx.y;
    const int j0 = blockIdx.x * 64;
    const float* Vb = V + ((size_t)bh << 16);
    for (int i = threadIdx.x; i < 1024; i += 256) {
        int jr = i >> 4, c4 = i & 15;
        float4 vv = *(const float4*)(Vb + (size_t)(j0 + jr) * DH + c4 * 4);
        float* dst = &sT[jr * 65 + c4 * 4];
        dst[0] = vv.x; dst[1] = vv.y; dst[2] = vv.z; dst[3] = vv.w;
    }
    __syncthreads();
    const int d = threadIdx.x >> 2, jseg = threadIdx.x & 3;
    ushort* dst = ws + OFF_VT + ((size_t)bh << 16) + (size_t)d * LSEQ + j0 + jseg * 16;
    #pragma unroll
    for (int g = 0; g < 4; ++g) {
        u16x4 o;
        #pragma unroll
        for (int e = 0; e < 4; ++e)
            o[e] = f2bf(sT[(jseg * 16 + g * 4 + e) * 65 + d]);
        *(u16x4*)(dst + g * 4) = o;
    }
}

// score_r = Q(head0) . REL^T, once per (b, row) -> bf16 table in ws
__global__ __launch_bounds__(256) void prep_sr(const float* __restrict__ REL,
                                               ushort* __restrict__ ws) {
    const int tid = threadIdx.x;
    const int w = tid >> 6, l = tid & 63, lg = l >> 4, lm = l & 15;
    const int it = blockIdx.x, b = blockIdx.y;
    const int i0 = it * TI;

    const ushort* Qh = ws + OFF_QH + (size_t)b * NH * LSEQ * DH;
    const ushort* Ql = ws + OFF_QL + (size_t)b * NH * LSEQ * DH;
    const float* RELb = REL + (size_t)b * NP * DH;
    ushort* SRb = ws + OFF_SR + (size_t)b * LSEQ * NP;

    bf16x8 qh[2], ql[2];
    #pragma unroll
    for (int ks = 0; ks < 2; ++ks) {
        size_t ao = (size_t)(i0 + lm) * DH + ks * 32 + lg * 8;
        qh[ks] = *(const bf16x8*)(Qh + ao);
        ql[ks] = *(const bf16x8*)(Ql + ao);
    }

    for (int ct = w; ct < 33; ct += 4) {
        int p0 = ct * 16;
        int prow = p0 + lm; if (prow > 512) prow = 512;
        f32x4 a0 = {0.f, 0.f, 0.f, 0.f};
        #pragma unroll
        for (int ks = 0; ks < 2; ++ks) {
            const float* bsrc = RELb + (size_t)prow * DH + ks * 32 + lg * 8;
            float4 v0 = *(const float4*)(bsrc);
            float4 v1 = *(const float4*)(bsrc + 4);
            float xs[8] = {v0.x, v0.y, v0.z, v0.w, v1.x, v1.y, v1.z, v1.w};
            bf16x8 bh8, bl8;
            #pragma unroll
            for (int e = 0; e < 8; ++e) {
                ushort hi = f2bf(xs[e]);
                bh8[e] = (short)hi;
                bl8[e] = (short)f2bf(xs[e] - bf2f(hi));
            }
            a0 = __builtin_amdgcn_mfma_f32_16x16x32_bf16(qh[ks], bh8, a0, 0, 0, 0);
            a0 = __builtin_amdgcn_mfma_f32_16x16x32_bf16(ql[ks], bh8, a0, 0, 0, 0);
            a0 = __builtin_amdgcn_mfma_f32_16x16x32_bf16(qh[ks], bl8, a0, 0, 0, 0);
        }
        if (p0 + lm < NP) {
            #pragma unroll
            for (int e = 0; e < 4; ++e)
                SRb[(size_t)(i0 + 4 * lg + e) * NP + p0 + lm] = f2bf(a0[e]);
        }
    }
}

// ---------------- main kernel ----------------

__global__ __launch_bounds__(NT, 4) void raa_main(
    const ushort* __restrict__ ws,
    const int* __restrict__ PM, const int* __restrict__ MASK,
    float* __restrict__ OUT_A, float* __restrict__ OUT_P)
{
    __shared__ float  X[TI * SRX];      // fp32 buckets (34.9 KB)
    __shared__ ushort sPb[TI * 1024];   // p bf16, chunk-swizzled (32.8 KB)
    __shared__ float  sAttn[TI * DH];   // 4 KB
    __shared__ float  sRedM[16 * 17];
    __shared__ float  sRedS[16 * 17];

    const int tid = threadIdx.x;
    const int w  = tid >> 6;
    const int l  = tid & 63;
    const int lg = l >> 4;
    const int lm = l & 15;

    const int it = blockIdx.x, h = blockIdx.y, b = blockIdx.z;
    const int i0 = it * TI;
    const int bh = b * NH + h;

    const ushort* Qh = ws + OFF_QH + (size_t)bh * LSEQ * DH;
    const ushort* Ql = ws + OFF_QL + (size_t)bh * LSEQ * DH;
    const ushort* Kh = ws + OFF_KH + (size_t)bh * LSEQ * DH;
    const ushort* Kl = ws + OFF_KL + (size_t)bh * LSEQ * DH;
    const ushort* Vt = ws + OFF_VT + (size_t)bh * DH * LSEQ;
    const ushort* Rt = ws + OFF_RT + (size_t)b * DH * RTC;
    const ushort* SRb = ws + OFF_SR + (size_t)b * LSEQ * NP;
    const int* PMb = PM + (size_t)b * LSEQ * LSEQ;
    const int* MKb = MASK + (size_t)b * LSEQ * LSEQ;

    // ---- early: zero buckets + attn accumulator ----
    #pragma unroll
    for (int z = 0; z < 9; ++z) {
        int idx = z * NT + tid;
        if (idx < TI * SRX) X[idx] = 0.f;
    }
    sAttn[tid] = 0.f;

    // ---- front-loaded global reads ----
    int pmr[16];
    float gf[16];
    {
        int mk[16]; ushort gu[16];
        #pragma unroll
        for (int t = 0; t < 4; ++t) {
            #pragma unroll
            for (int e = 0; e < 4; ++e) {
                int col = (4 * w + t) * 16 + lm;
                int row = 4 * lg + e;
                size_t off = (size_t)(i0 + row) * LSEQ + col;
                pmr[t * 4 + e] = PMb[off];
                mk[t * 4 + e]  = MKb[off];
            }
        }
        #pragma unroll
        for (int i = 0; i < 16; ++i) {
            int row = 4 * lg + (i & 3);
            gu[i] = SRb[(size_t)(i0 + row) * NP + pmr[i]];
        }
        #pragma unroll
        for (int i = 0; i < 16; ++i)
            gf[i] = mk[i] ? bf2f(gu[i]) : -3e38f;
    }

    bf16x8 qhh[2], qhl[2];
    #pragma unroll
    for (int ks = 0; ks < 2; ++ks) {
        size_t ao = (size_t)(i0 + lm) * DH + ks * 32 + lg * 8;
        qhh[ks] = *(const bf16x8*)(Qh + ao);
        qhl[ks] = *(const bf16x8*)(Ql + ao);
    }

    // ---- QK^T (K frags prefetched one coltile ahead) ----
    f32x4 acc[4];
    bf16x8 kh_c[2], kl_c[2], kh_n[2], kl_n[2];
    {
        size_t bo = (size_t)(4 * w * 16 + lm) * DH + lg * 8;
        kh_c[0] = *(const bf16x8*)(Kh + bo);      kl_c[0] = *(const bf16x8*)(Kl + bo);
        kh_c[1] = *(const bf16x8*)(Kh + bo + 32); kl_c[1] = *(const bf16x8*)(Kl + bo + 32);
    }
    #pragma unroll
    for (int t = 0; t < 4; ++t) {
        if (t < 3) {
            size_t bo = (size_t)((4 * w + t + 1) * 16 + lm) * DH + lg * 8;
            kh_n[0] = *(const bf16x8*)(Kh + bo);      kl_n[0] = *(const bf16x8*)(Kl + bo);
            kh_n[1] = *(const bf16x8*)(Kh + bo + 32); kl_n[1] = *(const bf16x8*)(Kl + bo + 32);
        }
        acc[t] = (f32x4){0.f, 0.f, 0.f, 0.f};
        #pragma unroll
        for (int ks = 0; ks < 2; ++ks) {
            acc[t] = __builtin_amdgcn_mfma_f32_16x16x32_bf16(qhh[ks], kh_c[ks], acc[t], 0, 0, 0);
            acc[t] = __builtin_amdgcn_mfma_f32_16x16x32_bf16(qhl[ks], kh_c[ks], acc[t], 0, 0, 0);
            acc[t] = __builtin_amdgcn_mfma_f32_16x16x32_bf16(qhh[ks], kl_c[ks], acc[t], 0, 0, 0);
        }
        #pragma unroll
        for (int ks = 0; ks < 2; ++ks) {
            kh_c[ks] = kh_n[ks]; kl_c[ks] = kl_n[ks];
        }
    }

    // ---- gather + mask + scale (all in registers) ----
    #pragma unroll
    for (int t = 0; t < 4; ++t) {
        #pragma unroll
        for (int e = 0; e < 4; ++e) {
            float g = gf[t * 4 + e];
            acc[t][e] = (g < -1e30f) ? -1e9f : (acc[t][e] + g) * 0.125f;
        }
    }

    // ---- softmax: wave-local (m,s), ONE barrier, lane-parallel combine ----
    float mw[4], c4v[4];
    #pragma unroll
    for (int e = 0; e < 4; ++e) {
        float m = fmaxf(fmaxf(acc[0][e], acc[1][e]), fmaxf(acc[2][e], acc[3][e]));
        #pragma unroll
        for (int o = 8; o >= 1; o >>= 1) m = fmaxf(m, __shfl_xor(m, o));
        mw[e] = m;
        float s = 0.f;
        #pragma unroll
        for (int t = 0; t < 4; ++t) {
            float v = __expf(acc[t][e] - m);
            acc[t][e] = v;
            s += v;
        }
        #pragma unroll
        for (int o = 8; o >= 1; o >>= 1) s += __shfl_xor(s, o);
        if (lm == 0) {
            sRedM[(4 * lg + e) * 17 + w] = m;
            sRedS[(4 * lg + e) * 17 + w] = s;
        }
    }
    __syncthreads();   // also covers X zero -> P5 atomics
    #pragma unroll
    for (int e = 0; e < 4; ++e) {
        int row = 4 * lg + e;
        float mv = sRedM[row * 17 + lm];   // lane lm holds wave lm's partial
        float sv = sRedS[row * 17 + lm];
        float m = mv;
        #pragma unroll
        for (int o = 8; o >= 1; o >>= 1) m = fmaxf(m, __shfl_xor(m, o));
        float sp = sv * __expf(mv - m);
        #pragma unroll
        for (int o = 8; o >= 1; o >>= 1) sp += __shfl_xor(sp, o);
        c4v[e] = __expf(mw[e] - m) / sp;
    }

    // ---- P5: p -> sPb(bf16) + bucket scatter ----
    #pragma unroll
    for (int t = 0; t < 4; ++t) {
        int col = (4 * w + t) * 16 + lm;
        #pragma unroll
        for (int e = 0; e < 4; ++e) {
            int row = 4 * lg + e;
            float p = acc[t][e] * c4v[e];
            sPb[row * 1024 + (((col >> 3) ^ (row & 7)) << 3) + (col & 7)] = f2bf(p);
            atomicAdd(&X[row * SRX + pmr[t * 4 + e]], p);
        }
    }
    __syncthreads();

    // ---- vectorized p_attn store (overlaps with P6 compute below) ----
    const size_t pbase = ((size_t)bh * LSEQ + i0) * LSEQ;
    #pragma unroll
    for (int g = 0; g < 4; ++g) {
        int elem = g * 4096 + tid * 4;
        int r = elem >> 10, cc = elem & 1023;
        int ad = r * 1024 + (((cc >> 3) ^ (r & 7)) << 3) + (cc & 7);
        u16x4 pv = *(const u16x4*)&sPb[ad];
        float4 o4 = make_float4(bf2f(pv[0]), bf2f(pv[1]), bf2f(pv[2]), bf2f(pv[3]));
        *(float4*)(OUT_P + pbase + (size_t)r * LSEQ + cc) = o4;
    }

    // ---- P6: waves 0-7: p@V (Vt); waves 8-15: buckets@REL (Rt) ----
    if (w < 8) {
        int ct = w >> 1, jh = w & 1;
        int d0 = ct * 16;
        f32x4 pa = {0.f, 0.f, 0.f, 0.f};
        #pragma unroll 4
        for (int ks = 0; ks < 16; ++ks) {
            int j0 = jh * 512 + ks * 32;
            int ch = (j0 >> 3) + lg;
            bf16x8 a = *(const bf16x8*)&sPb[lm * 1024 + ((ch ^ (lm & 7)) << 3)];
            bf16x8 bb = *(const bf16x8*)(Vt + (size_t)(d0 + lm) * LSEQ + j0 + lg * 8);
            pa = __builtin_amdgcn_mfma_f32_16x16x32_bf16(a, bb, pa, 0, 0, 0);
        }
        #pragma unroll
        for (int e = 0; e < 4; ++e)
            atomicAdd(&sAttn[(4 * lg + e) * DH + d0 + lm], pa[e]);
    } else {
        int ct = (w - 8) >> 1, ph = w & 1;
        int d0 = ct * 16;
        int nks = ph ? 8 : 9;
        int pb0 = ph ? 288 : 0;
        f32x4 pa = {0.f, 0.f, 0.f, 0.f};
        for (int ks = 0; ks < nks; ++ks) {
            int p0 = pb0 + ks * 32;
            bf16x8 a;
            #pragma unroll
            for (int e = 0; e < 8; ++e)
                a[e] = (short)f2bf(X[lm * SRX + p0 + lg * 8 + e]);
            bf16x8 bb = *(const bf16x8*)(Rt + (size_t)(d0 + lm) * RTC + p0 + lg * 8);
            pa = __builtin_amdgcn_mfma_f32_16x16x32_bf16(a, bb, pa, 0, 0, 0);
        }
        #pragma unroll
        for (int e = 0; e < 4; ++e)
            atomicAdd(&sAttn[(4 * lg + e) * DH + d0 + lm], pa[e]);
    }
    __syncthreads();

    OUT_A[((size_t)bh * LSEQ + i0 + (tid >> 6)) * DH + (tid & 63)] = sAttn[tid];
}

// ---------------- fallback (self-contained, from R2) ----------------

__global__ __launch_bounds__(NT, 4) void raa_fallback(
    const float* __restrict__ Q, const float* __restrict__ K,
    const float* __restrict__ V, const float* __restrict__ REL,
    const int* __restrict__ PM, const int* __restrict__ MASK,
    float* __restrict__ OUT_A, float* __restrict__ OUT_P)
{
    __shared__ ushort sQh[TI * 64];
    __shared__ ushort sQl[TI * 64];
    __shared__ float  sR[TI * NP];
    __shared__ ushort sPb[TI * 1024];
    __shared__ float  sAttn[TI * 64];
    __shared__ float  sRed[16 * 17];
    __shared__ float  sFin[16];

    const int tid = threadIdx.x;
    const int w  = tid >> 6;
    const int l  = tid & 63;
    const int lg = l >> 4;
    const int lm = l & 15;

    const int it = blockIdx.x, h = blockIdx.y, b = blockIdx.z;
    const int i0 = it * TI;

    const float* Qb0  = Q + ((size_t)b * NH + 0) * LSEQ * DH;
    const float* Qbh  = Q + ((size_t)b * NH + h) * LSEQ * DH;
    const float* Kbh  = K + ((size_t)b * NH + h) * LSEQ * DH;
    const float* Vbh  = V + ((size_t)b * NH + h) * LSEQ * DH;
    const float* RELb = REL + (size_t)b * NP * DH;
    const int*   PMb  = PM  + (size_t)b * LSEQ * LSEQ;
    const int*   MKb  = MASK + (size_t)b * LSEQ * LSEQ;

    {
        int row = tid >> 6, kk = tid & 63;
        float x = Qb0[(size_t)(i0 + row) * DH + kk];
        ushort hi = f2bf(x);
        ushort lo = f2bf(x - bf2f(hi));
        int ad = row * 64 + (((kk >> 3) ^ (row & 7)) << 3) + (kk & 7);
        sQh[ad] = hi; sQl[ad] = lo;
        sAttn[tid] = 0.f;
    }
    __syncthreads();

    bf16x8 qh[2], ql[2];
    #pragma unroll
    for (int ks = 0; ks < 2; ++ks) {
        int ch = lg + 4 * ks;
        int ad = lm * 64 + ((ch ^ (lm & 7)) << 3);
        qh[ks] = *(const bf16x8*)&sQh[ad];
        ql[ks] = *(const bf16x8*)&sQl[ad];
    }
    __syncthreads();

    {
        int row = tid >> 6, kk = tid & 63;
        float x = Qbh[(size_t)(i0 + row) * DH + kk];
        ushort hi = f2bf(x);
        ushort lo = f2bf(x - bf2f(hi));
        int ad = row * 64 + (((kk >> 3) ^ (row & 7)) << 3) + (kk & 7);
        sQh[ad] = hi; sQl[ad] = lo;
    }

    for (int ct = w; ct < 33; ct += 16) {
        int p0 = ct * 16;
        int prow = p0 + lm; if (prow > 512) prow = 512;
        const float* bsrc = RELb + (size_t)prow * DH + 8 * lg;
        f32x4 acc = {0.f, 0.f, 0.f, 0.f};
        #pragma unroll
        for (int ks = 0; ks < 2; ++ks) {
            float4 v0 = *(const float4*)(bsrc + ks * 32);
            float4 v1 = *(const float4*)(bsrc + ks * 32 + 4);
            float xs[8] = {v0.x, v0.y, v0.z, v0.w, v1.x, v1.y, v1.z, v1.w};
            bf16x8 bh, bl;
            #pragma unroll
            for (int e = 0; e < 8; ++e) {
                ushort hi = f2bf(xs[e]);
                bh[e] = (short)hi;
                bl[e] = (short)f2bf(xs[e] - bf2f(hi));
            }
            acc = __builtin_amdgcn_mfma_f32_16x16x32_bf16(qh[ks], bh, acc, 0, 0, 0);
            acc = __builtin_amdgcn_mfma_f32_16x16x32_bf16(ql[ks], bh, acc, 0, 0, 0);
            acc = __builtin_amdgcn_mfma_f32_16x16x32_bf16(qh[ks], bl, acc, 0, 0, 0);
        }
        int pcol = p0 + lm;
        if (pcol < NP) {
            #pragma unroll
            for (int e = 0; e < 4; ++e)
                sR[(4 * lg + e) * NP + pcol] = acc[e];
        }
    }
    __syncthreads();

    #pragma unroll
    for (int ks = 0; ks < 2; ++ks) {
        int ch = lg + 4 * ks;
        int ad = lm * 64 + ((ch ^ (lm & 7)) << 3);
        qh[ks] = *(const bf16x8*)&sQh[ad];
        ql[ks] = *(const bf16x8*)&sQl[ad];
    }
    f32x4 acc[4];
    #pragma unroll
    for (int t = 0; t < 4; ++t) {
        int j = (4 * w + t) * 16 + lm;
        const float* bsrc = Kbh + (size_t)j * DH + 8 * lg;
        acc[t] = (f32x4){0.f, 0.f, 0.f, 0.f};
        #pragma unroll
        for (int ks = 0; ks < 2; ++ks) {
            float4 v0 = *(const float4*)(bsrc + ks * 32);
            float4 v1 = *(const float4*)(bsrc + ks * 32 + 4);
            float xs[8] = {v0.x, v0.y, v0.z, v0.w, v1.x, v1.y, v1.z, v1.w};
            bf16x8 bh, bl;
            #pragma unroll
            for (int e = 0; e < 8; ++e) {
                ushort hi = f2bf(xs[e]);
                bh[e] = (short)hi;
                bl[e] = (short)f2bf(xs[e] - bf2f(hi));
            }
            acc[t] = __builtin_amdgcn_mfma_f32_16x16x32_bf16(qh[ks], bh, acc[t], 0, 0, 0);
            acc[t] = __builtin_amdgcn_mfma_f32_16x16x32_bf16(ql[ks], bh, acc[t], 0, 0, 0);
            acc[t] = __builtin_amdgcn_mfma_f32_16x16x32_bf16(qh[ks], bl, acc[t], 0, 0, 0);
        }
    }

    #pragma unroll
    for (int t = 0; t < 4; ++t) {
        int col = (4 * w + t) * 16 + lm;
        #pragma unroll
        for (int e = 0; e < 4; ++e) {
            int row = 4 * lg + e;
            size_t off = (size_t)(i0 + row) * LSEQ + col;
            int pm = PMb[off];
            int mk = MKb[off];
            float g = sR[row * NP + pm];
            acc[t][e] = (mk == 0) ? -1e9f : (acc[t][e] + g) * 0.125f;
        }
    }
    __syncthreads();
    for (int idx = tid; idx < TI * NP; idx += NT) sR[idx] = 0.f;
    __syncthreads();

    float Mr[4];
    #pragma unroll
    for (int e = 0; e < 4; ++e) {
        float m = fmaxf(fmaxf(acc[0][e], acc[1][e]), fmaxf(acc[2][e], acc[3][e]));
        #pragma unroll
        for (int o = 8; o >= 1; o >>= 1) m = fmaxf(m, __shfl_xor(m, o));
        Mr[e] = m;
    }
    if (lm == 0) {
        #pragma unroll
        for (int e = 0; e < 4; ++e) sRed[(4 * lg + e) * 17 + w] = Mr[e];
    }
    __syncthreads();
    if (w == 0 && l < 16) {
        float m = -INFINITY;
        for (int ww = 0; ww < 16; ++ww) m = fmaxf(m, sRed[l * 17 + ww]);
        sFin[l] = m;
    }
    __syncthreads();
    #pragma unroll
    for (int e = 0; e < 4; ++e) Mr[e] = sFin[4 * lg + e];

    float Sr[4];
    #pragma unroll
    for (int e = 0; e < 4; ++e) {
        float s = 0.f;
        #pragma unroll
        for (int t = 0; t < 4; ++t) {
            float v = __expf(acc[t][e] - Mr[e]);
            acc[t][e] = v;
            s += v;
        }
        #pragma unroll
        for (int o = 8; o >= 1; o >>= 1) s += __shfl_xor(s, o);
        Sr[e] = s;
    }
    if (lm == 0) {
        #pragma unroll
        for (int e = 0; e < 4; ++e) sRed[(4 * lg + e) * 17 + w] = Sr[e];
    }
    __syncthreads();
    if (w == 0 && l < 16) {
        float s = 0.f;
        for (int ww = 0; ww < 16; ++ww) s += sRed[l * 17 + ww];
        sFin[l] = s;
    }
    __syncthreads();

    float inv[4];
    #pragma unroll
    for (int e = 0; e < 4; ++e) inv[e] = 1.0f / sFin[4 * lg + e];

    const size_t pbase = (((size_t)b * NH + h) * LSEQ + i0) * LSEQ;
    #pragma unroll
    for (int t = 0; t < 4; ++t) {
        int col = (4 * w + t) * 16 + lm;
        #pragma unroll
        for (int e = 0; e < 4; ++e) {
            int row = 4 * lg + e;
            float p = acc[t][e] * inv[e];
            OUT_P[pbase + (size_t)row * LSEQ + col] = p;
            int ad = row * 1024 + (((col >> 3) ^ (row & 7)) << 3) + (col & 7);
            sPb[ad] = f2bf(p);
            int pm = PMb[(size_t)(i0 + row) * LSEQ + col];
            atomicAdd(&sR[row * NP + pm], p);
        }
    }
    __syncthreads();

    if (w < 8) {
        int ct = w >> 1, jh = w & 1;
        int d = ct * 16 + lm;
        f32x4 pa = {0.f, 0.f, 0.f, 0.f};
        for (int ks = 0; ks < 16; ++ks) {
            int j0 = jh * 512 + ks * 32;
            int ch = (j0 >> 3) + lg;
            bf16x8 a = *(const bf16x8*)&sPb[lm * 1024 + ((ch ^ (lm & 7)) << 3)];
            const float* vs = Vbh + (size_t)(j0 + 8 * lg) * DH + d;
            bf16x8 bb;
            #pragma unroll
            for (int e = 0; e < 8; ++e) bb[e] = (short)f2bf(vs[(size_t)e * DH]);
            pa = __builtin_amdgcn_mfma_f32_16x16x32_bf16(a, bb, pa, 0, 0, 0);
        }
        #pragma unroll
        for (int e = 0; e < 4; ++e)
            atomicAdd(&sAttn[(4 * lg + e) * 64 + d], pa[e]);
    } else {
        int ct = (w - 8) >> 1, ph = w & 1;
        int d = ct * 16 + lm;
        int nks = ph ? 9 : 8;
        f32x4 pa = {0.f, 0.f, 0.f, 0.f};
        for (int ks = 0; ks < nks; ++ks) {
            int p0 = ph * 256 + ks * 32 + 8 * lg;
            bf16x8 a, bb;
            #pragma unroll
            for (int e = 0; e < 8; ++e) {
                int pp = p0 + e;
                float av = (pp < NP) ? sR[lm * NP + pp] : 0.f;
                a[e] = (short)f2bf(av);
                int pc = (pp < NP) ? pp : (NP - 1);
                bb[e] = (short)f2bf(RELb[(size_t)pc * DH + d]);
            }
            pa = __builtin_amdgcn_mfma_f32_16x16x32_bf16(a, bb, pa, 0, 0, 0);
        }
        #pragma unroll
        for (int e = 0; e < 4; ++e)
            atomicAdd(&sAttn[(4 * lg + e) * 64 + d], pa[e]);
    }
    __syncthreads();

    {
        int row = tid >> 6, col = tid & 63;
        OUT_A[(((size_t)b * NH + h) * LSEQ + i0 + row) * DH + col] =
            sAttn[row * 64 + col];
    }
}

extern "C" void kernel_launch(void* const* d_in, const int* in_sizes, int n_in,
                              void* d_out, int out_size, void* d_ws, size_t ws_size,
                              hipStream_t stream) {
    const float* q    = (const float*)d_in[0];
    const float* k    = (const float*)d_in[1];
    const float* v    = (const float*)d_in[2];
    const float* rel  = (const float*)d_in[3];
    const int*   pm   = (const int*)d_in[4];
    const int*   mask = (const int*)d_in[5];
    float* out_a = (float*)d_out;
    float* out_p = (float*)d_out + (size_t)BSZ * NH * LSEQ * DH;

    dim3 grid(LSEQ / TI, NH, BSZ);
    if (ws_size >= WS_NEED && d_ws != nullptr) {
        ushort* ws = (ushort*)d_ws;
        prep_qk<<<2048, 256, 0, stream>>>(q, k, ws);
        prep_vt<<<dim3(16, 32), 256, 0, stream>>>(v, ws);
        prep_rt<<<256, 256, 0, stream>>>(rel, ws);
        prep_sr<<<dim3(LSEQ / TI, BSZ), 256, 0, stream>>>(rel, ws);
        raa_main<<<grid, NT, 0, stream>>>((const ushort*)ws, pm, mask, out_a, out_p);
    } else {
        raa_fallback<<<grid, NT, 0, stream>>>(q, k, v, rel, pm, mask, out_a, out_p);
    }
}

// Round 5
// 555.559 us; speedup vs baseline: 2.8366x; 1.0244x over previous
//
#include <hip/hip_runtime.h>

// RelationAwareAttention: BS=4,H=8,L=1024,D=64,P=513, fp32 in/out.
// out = [attn_sum (B,H,L,D) | p_attn (B,H,L,L)] flat fp32.
//
// R5: prep1 (one launch, job-split): Qh/Ql,Kh/Kl bf16 planes; Vt (V^T bf16);
//     Rt (REL^T bf16, padded); SR (score_r = Q0.REL^T, bf16, once per b).
//     prep2: GP[b,i,j] = packed (bf16 gathered-score | u16 pm), mask folded,
//     gathered from an LDS-resident SR slab.  Main kernel reads ONE coalesced
//     u32 stream for gather+mask+pm; QK^T/PV/bucket GEMMs all MFMA from
//     contiguous 16B loads. Fallback if ws too small.

#define BSZ 4
#define NH 8
#define LSEQ 1024
#define DH 64
#define NP 513
#define TI 16
#define NT 1024
#define SRX 548            // LDS bucket row stride (floats): 16B-aligned rows
#define RTC 544            // Rt padded cols

#define NQE (BSZ*NH*LSEQ*DH)   // 2097152 elems per plane
#define NRT (BSZ*DH*RTC)       // 139264
#define NSR (BSZ*LSEQ*NP)      // 2101248
#define NGPW (2*BSZ*LSEQ*LSEQ) // GP span in ushort units (8388608)
#define OFF_QH 0
#define OFF_QL (NQE)
#define OFF_KH (2*NQE)
#define OFF_KL (3*NQE)
#define OFF_VT (4*NQE)
#define OFF_RT (5*NQE)
#define OFF_SR (5*NQE + NRT)
#define OFF_GP (5*NQE + NRT + NSR)     // even -> 4B aligned
#define WS_NEED ((size_t)(OFF_GP + NGPW) * 2)

#define NB_QK 4096
#define NB_VT 512
#define NB_RT 544
#define NB_SR 256
#define NB_P1 (NB_QK + NB_VT + NB_RT + NB_SR)

typedef __attribute__((ext_vector_type(8))) short bf16x8;
typedef __attribute__((ext_vector_type(4))) float f32x4;
typedef __attribute__((ext_vector_type(4))) ushort u16x4;
typedef __attribute__((ext_vector_type(4))) uint u32x4;

__device__ __forceinline__ ushort f2bf(float x) {
    uint u = __float_as_uint(x);
    u += 0x7FFFu + ((u >> 16) & 1u);
    return (ushort)(u >> 16);
}
__device__ __forceinline__ float bf2f(ushort h) {
    return __uint_as_float(((uint)h) << 16);
}

// ---------------- prep1: qk planes | vt | rt | sr  (job-split) ----------------

__global__ __launch_bounds__(256) void prep1(
    const float* __restrict__ Q, const float* __restrict__ K,
    const float* __restrict__ V, const float* __restrict__ REL,
    ushort* __restrict__ ws)
{
    __shared__ float sT[64 * 65];
    const int bid = blockIdx.x;
    const int tid = threadIdx.x;

    if (bid < NB_QK) {
        // ---- job A: Q/K -> bf16 hi/lo planes ----
        const int n4 = NQE / 4;
        int i = bid * 256 + tid;           // < 2*n4 exactly
        int isK = i >= n4;
        int base = i - isK * n4;
        float4 v = ((const float4*)(isK ? K : Q))[base];
        float xs[4] = {v.x, v.y, v.z, v.w};
        u16x4 hh, ll;
        #pragma unroll
        for (int e = 0; e < 4; ++e) {
            ushort hi = f2bf(xs[e]);
            hh[e] = hi;
            ll[e] = f2bf(xs[e] - bf2f(hi));
        }
        *(u16x4*)(ws + (isK ? OFF_KH : OFF_QH) + (size_t)base * 4) = hh;
        *(u16x4*)(ws + (isK ? OFF_KL : OFF_QL) + (size_t)base * 4) = ll;
    } else if (bid < NB_QK + NB_VT) {
        // ---- job B: V transpose (LDS tile) ----
        const int vb = bid - NB_QK;
        const int bh = vb >> 4;
        const int j0 = (vb & 15) * 64;
        const float* Vb = V + ((size_t)bh << 16);
        for (int i = tid; i < 1024; i += 256) {
            int jr = i >> 4, c4 = i & 15;
            float4 vv = *(const float4*)(Vb + (size_t)(j0 + jr) * DH + c4 * 4);
            float* dst = &sT[jr * 65 + c4 * 4];
            dst[0] = vv.x; dst[1] = vv.y; dst[2] = vv.z; dst[3] = vv.w;
        }
        __syncthreads();
        const int d = tid >> 2, jseg = tid & 3;
        ushort* dst = ws + OFF_VT + ((size_t)bh << 16) + (size_t)d * LSEQ + j0 + jseg * 16;
        #pragma unroll
        for (int g = 0; g < 4; ++g) {
            u16x4 o;
            #pragma unroll
            for (int e = 0; e < 4; ++e)
                o[e] = f2bf(sT[(jseg * 16 + g * 4 + e) * 65 + d]);
            *(u16x4*)(dst + g * 4) = o;
        }
    } else if (bid < NB_QK + NB_VT + NB_RT) {
        // ---- job C: REL transpose (padded) ----
        int i = (bid - NB_QK - NB_VT) * 256 + tid;   // < NRT exactly
        int b = i / (DH * RTC);
        int r = i - b * (DH * RTC);
        int d = r / RTC;
        int p = r - d * RTC;
        float x = (p < NP) ? REL[((size_t)b * NP + p) * DH + d] : 0.f;
        ws[OFF_RT + i] = f2bf(x);
    } else {
        // ---- job D: SR = Q(head0) . REL^T (split-bf16), bf16 table ----
        const int sb = bid - (NB_QK + NB_VT + NB_RT);
        const int it = sb & 63, b = sb >> 6;
        const int i0 = it * TI;
        const int w = tid >> 6, l = tid & 63, lg = l >> 4, lm = l & 15;

        const float* Qb0 = Q + ((size_t)b * NH) * LSEQ * DH;
        const float* RELb = REL + (size_t)b * NP * DH;
        ushort* SRb = ws + OFF_SR + (size_t)b * LSEQ * NP;

        bf16x8 qh[2], ql[2];
        #pragma unroll
        for (int ks = 0; ks < 2; ++ks) {
            const float* qs = Qb0 + (size_t)(i0 + lm) * DH + ks * 32 + lg * 8;
            float4 v0 = *(const float4*)(qs);
            float4 v1 = *(const float4*)(qs + 4);
            float xs[8] = {v0.x, v0.y, v0.z, v0.w, v1.x, v1.y, v1.z, v1.w};
            #pragma unroll
            for (int e = 0; e < 8; ++e) {
                ushort hi = f2bf(xs[e]);
                qh[ks][e] = (short)hi;
                ql[ks][e] = (short)f2bf(xs[e] - bf2f(hi));
            }
        }

        for (int ct = w; ct < 33; ct += 4) {
            int p0 = ct * 16;
            int prow = p0 + lm; if (prow > 512) prow = 512;
            f32x4 a0 = {0.f, 0.f, 0.f, 0.f};
            #pragma unroll
            for (int ks = 0; ks < 2; ++ks) {
                const float* bsrc = RELb + (size_t)prow * DH + ks * 32 + lg * 8;
                float4 v0 = *(const float4*)(bsrc);
                float4 v1 = *(const float4*)(bsrc + 4);
                float xs[8] = {v0.x, v0.y, v0.z, v0.w, v1.x, v1.y, v1.z, v1.w};
                bf16x8 bh8, bl8;
                #pragma unroll
                for (int e = 0; e < 8; ++e) {
                    ushort hi = f2bf(xs[e]);
                    bh8[e] = (short)hi;
                    bl8[e] = (short)f2bf(xs[e] - bf2f(hi));
                }
                a0 = __builtin_amdgcn_mfma_f32_16x16x32_bf16(qh[ks], bh8, a0, 0, 0, 0);
                a0 = __builtin_amdgcn_mfma_f32_16x16x32_bf16(ql[ks], bh8, a0, 0, 0, 0);
                a0 = __builtin_amdgcn_mfma_f32_16x16x32_bf16(qh[ks], bl8, a0, 0, 0, 0);
            }
            if (p0 + lm < NP) {
                #pragma unroll
                for (int e = 0; e < 4; ++e)
                    SRb[(size_t)(i0 + 4 * lg + e) * NP + p0 + lm] = f2bf(a0[e]);
            }
        }
    }
}

// ---------------- prep2: GP = packed (bf16 gathered score_r | u16 pm) --------

__global__ __launch_bounds__(256) void prep2(
    const int* __restrict__ PM, const int* __restrict__ MASK,
    ushort* __restrict__ ws)
{
    __shared__ ushort sSR[4 * 520];
    const int tid = threadIdx.x;
    const int bid = blockIdx.x;            // 1024 blocks: 256 row-groups x 4 b
    const int b = bid >> 8;
    const int row0 = (bid & 255) * 4;

    const ushort* SRb = ws + OFF_SR + (size_t)b * LSEQ * NP;
    uint* GPb = (uint*)(ws + OFF_GP) + (size_t)b * LSEQ * LSEQ;
    const int* PMb = PM + (size_t)b * LSEQ * LSEQ;
    const int* MKb = MASK + (size_t)b * LSEQ * LSEQ;

    for (int i = tid; i < 4 * 520; i += 256) {
        int row = i / 520, col = i - row * 520;
        if (col < NP) sSR[row * 520 + col] = SRb[(size_t)(row0 + row) * NP + col];
    }
    __syncthreads();

    #pragma unroll
    for (int r = 0; r < 4; ++r) {
        int idx4 = r * 256 + tid;          // 1024 int4 groups = 4096 elems
        int row = idx4 >> 8;
        int c0 = (idx4 & 255) * 4;
        size_t off = (size_t)(row0 + row) * LSEQ + c0;
        int4 pm4 = *(const int4*)(PMb + off);
        int4 mk4 = *(const int4*)(MKb + off);
        const ushort* srow = &sSR[row * 520];
        u32x4 o;
        o[0] = ((uint)(mk4.x ? srow[pm4.x] : 0xFF62u) << 16) | (uint)pm4.x;
        o[1] = ((uint)(mk4.y ? srow[pm4.y] : 0xFF62u) << 16) | (uint)pm4.y;
        o[2] = ((uint)(mk4.z ? srow[pm4.z] : 0xFF62u) << 16) | (uint)pm4.z;
        o[3] = ((uint)(mk4.w ? srow[pm4.w] : 0xFF62u) << 16) | (uint)pm4.w;
        *(u32x4*)(GPb + off) = o;
    }
}

// ---------------- main kernel ----------------

__global__ __launch_bounds__(NT, 4) void raa_main(
    const ushort* __restrict__ ws,
    float* __restrict__ OUT_A, float* __restrict__ OUT_P)
{
    __shared__ float  X[TI * SRX];      // fp32 buckets (35 KB)
    __shared__ ushort sPb[TI * 1024];   // p bf16, chunk-swizzled (32.8 KB)
    __shared__ float  sAttn[TI * DH];   // 4 KB
    __shared__ float  sRedM[16 * 17];
    __shared__ float  sRedS[16 * 17];

    const int tid = threadIdx.x;
    const int w  = tid >> 6;
    const int l  = tid & 63;
    const int lg = l >> 4;
    const int lm = l & 15;

    const int it = blockIdx.x, h = blockIdx.y, b = blockIdx.z;
    const int i0 = it * TI;
    const int bh = b * NH + h;

    const ushort* Qh = ws + OFF_QH + (size_t)bh * LSEQ * DH;
    const ushort* Ql = ws + OFF_QL + (size_t)bh * LSEQ * DH;
    const ushort* Kh = ws + OFF_KH + (size_t)bh * LSEQ * DH;
    const ushort* Kl = ws + OFF_KL + (size_t)bh * LSEQ * DH;
    const ushort* Vt = ws + OFF_VT + (size_t)bh * DH * LSEQ;
    const ushort* Rt = ws + OFF_RT + (size_t)b * DH * RTC;
    const uint*   GPb = (const uint*)(ws + OFF_GP) + (size_t)b * LSEQ * LSEQ;

    // ---- early: zero buckets + attn accumulator ----
    #pragma unroll
    for (int z = 0; z < 9; ++z) {
        int idx = z * NT + tid;
        if (idx < TI * SRX) X[idx] = 0.f;
    }
    sAttn[tid] = 0.f;

    // ---- front-loaded: one coalesced packed stream (gather+mask+pm) ----
    uint gp[16];
    #pragma unroll
    for (int t = 0; t < 4; ++t) {
        #pragma unroll
        for (int e = 0; e < 4; ++e) {
            int col = (4 * w + t) * 16 + lm;
            int row = 4 * lg + e;
            gp[t * 4 + e] = GPb[(size_t)(i0 + row) * LSEQ + col];
        }
    }

    bf16x8 qhh[2], qhl[2];
    #pragma unroll
    for (int ks = 0; ks < 2; ++ks) {
        size_t ao = (size_t)(i0 + lm) * DH + ks * 32 + lg * 8;
        qhh[ks] = *(const bf16x8*)(Qh + ao);
        qhl[ks] = *(const bf16x8*)(Ql + ao);
    }

    // ---- QK^T (K frags prefetched one coltile ahead) ----
    f32x4 acc[4];
    bf16x8 kh_c[2], kl_c[2], kh_n[2], kl_n[2];
    {
        size_t bo = (size_t)(4 * w * 16 + lm) * DH + lg * 8;
        kh_c[0] = *(const bf16x8*)(Kh + bo);      kl_c[0] = *(const bf16x8*)(Kl + bo);
        kh_c[1] = *(const bf16x8*)(Kh + bo + 32); kl_c[1] = *(const bf16x8*)(Kl + bo + 32);
    }
    #pragma unroll
    for (int t = 0; t < 4; ++t) {
        if (t < 3) {
            size_t bo = (size_t)((4 * w + t + 1) * 16 + lm) * DH + lg * 8;
            kh_n[0] = *(const bf16x8*)(Kh + bo);      kl_n[0] = *(const bf16x8*)(Kl + bo);
            kh_n[1] = *(const bf16x8*)(Kh + bo + 32); kl_n[1] = *(const bf16x8*)(Kl + bo + 32);
        }
        acc[t] = (f32x4){0.f, 0.f, 0.f, 0.f};
        #pragma unroll
        for (int ks = 0; ks < 2; ++ks) {
            acc[t] = __builtin_amdgcn_mfma_f32_16x16x32_bf16(qhh[ks], kh_c[ks], acc[t], 0, 0, 0);
            acc[t] = __builtin_amdgcn_mfma_f32_16x16x32_bf16(qhl[ks], kh_c[ks], acc[t], 0, 0, 0);
            acc[t] = __builtin_amdgcn_mfma_f32_16x16x32_bf16(qhh[ks], kl_c[ks], acc[t], 0, 0, 0);
        }
        #pragma unroll
        for (int ks = 0; ks < 2; ++ks) {
            kh_c[ks] = kh_n[ks]; kl_c[ks] = kl_n[ks];
        }
    }

    // ---- gather + mask + scale (all in registers, from packed gp) ----
    #pragma unroll
    for (int i = 0; i < 16; ++i) {
        int t = i >> 2, e = i & 3;
        float g = bf2f((ushort)(gp[i] >> 16));
        acc[t][e] = (g < -1e30f) ? -1e9f : (acc[t][e] + g) * 0.125f;
    }

    // ---- softmax: wave-local (m,s), ONE barrier, lane-parallel combine ----
    float mw[4], c4v[4];
    #pragma unroll
    for (int e = 0; e < 4; ++e) {
        float m = fmaxf(fmaxf(acc[0][e], acc[1][e]), fmaxf(acc[2][e], acc[3][e]));
        #pragma unroll
        for (int o = 8; o >= 1; o >>= 1) m = fmaxf(m, __shfl_xor(m, o));
        mw[e] = m;
        float s = 0.f;
        #pragma unroll
        for (int t = 0; t < 4; ++t) {
            float v = __expf(acc[t][e] - m);
            acc[t][e] = v;
            s += v;
        }
        #pragma unroll
        for (int o = 8; o >= 1; o >>= 1) s += __shfl_xor(s, o);
        if (lm == 0) {
            sRedM[(4 * lg + e) * 17 + w] = m;
            sRedS[(4 * lg + e) * 17 + w] = s;
        }
    }
    __syncthreads();   // also covers X zero -> P5 atomics
    #pragma unroll
    for (int e = 0; e < 4; ++e) {
        int row = 4 * lg + e;
        float mv = sRedM[row * 17 + lm];
        float sv = sRedS[row * 17 + lm];
        float m = mv;
        #pragma unroll
        for (int o = 8; o >= 1; o >>= 1) m = fmaxf(m, __shfl_xor(m, o));
        float sp = sv * __expf(mv - m);
        #pragma unroll
        for (int o = 8; o >= 1; o >>= 1) sp += __shfl_xor(sp, o);
        c4v[e] = __expf(mw[e] - m) / sp;
    }

    // ---- P5: p -> sPb(bf16) + bucket scatter (pm from packed gp) ----
    #pragma unroll
    for (int t = 0; t < 4; ++t) {
        int col = (4 * w + t) * 16 + lm;
        #pragma unroll
        for (int e = 0; e < 4; ++e) {
            int row = 4 * lg + e;
            float p = acc[t][e] * c4v[e];
            sPb[row * 1024 + (((col >> 3) ^ (row & 7)) << 3) + (col & 7)] = f2bf(p);
            atomicAdd(&X[row * SRX + (int)(gp[t * 4 + e] & 0xFFFFu)], p);
        }
    }
    __syncthreads();

    // ---- vectorized p_attn store (overlaps with P6 compute below) ----
    const size_t pbase = ((size_t)bh * LSEQ + i0) * LSEQ;
    #pragma unroll
    for (int g = 0; g < 4; ++g) {
        int elem = g * 4096 + tid * 4;
        int r = elem >> 10, cc = elem & 1023;
        int ad = r * 1024 + (((cc >> 3) ^ (r & 7)) << 3) + (cc & 7);
        u16x4 pv = *(const u16x4*)&sPb[ad];
        float4 o4 = make_float4(bf2f(pv[0]), bf2f(pv[1]), bf2f(pv[2]), bf2f(pv[3]));
        *(float4*)(OUT_P + pbase + (size_t)r * LSEQ + cc) = o4;
    }

    // ---- P6: waves 0-7: p@V (Vt); waves 8-15: buckets@REL (Rt) ----
    if (w < 8) {
        int ct = w >> 1, jh = w & 1;
        int d0 = ct * 16;
        f32x4 pa = {0.f, 0.f, 0.f, 0.f};
        #pragma unroll 4
        for (int ks = 0; ks < 16; ++ks) {
            int j0 = jh * 512 + ks * 32;
            int ch = (j0 >> 3) + lg;
            bf16x8 a = *(const bf16x8*)&sPb[lm * 1024 + ((ch ^ (lm & 7)) << 3)];
            bf16x8 bb = *(const bf16x8*)(Vt + (size_t)(d0 + lm) * LSEQ + j0 + lg * 8);
            pa = __builtin_amdgcn_mfma_f32_16x16x32_bf16(a, bb, pa, 0, 0, 0);
        }
        #pragma unroll
        for (int e = 0; e < 4; ++e)
            atomicAdd(&sAttn[(4 * lg + e) * DH + d0 + lm], pa[e]);
    } else {
        int ct = (w - 8) >> 1, ph = w & 1;
        int d0 = ct * 16;
        int nks = ph ? 8 : 9;
        int pb0 = ph ? 288 : 0;
        f32x4 pa = {0.f, 0.f, 0.f, 0.f};
        for (int ks = 0; ks < nks; ++ks) {
            int p0 = pb0 + ks * 32;
            float x8[8];
            *(float4*)&x8[0] = *(const float4*)&X[lm * SRX + p0 + lg * 8];
            *(float4*)&x8[4] = *(const float4*)&X[lm * SRX + p0 + lg * 8 + 4];
            bf16x8 a;
            #pragma unroll
            for (int e = 0; e < 8; ++e)
                a[e] = (short)f2bf(x8[e]);
            bf16x8 bb = *(const bf16x8*)(Rt + (size_t)(d0 + lm) * RTC + p0 + lg * 8);
            pa = __builtin_amdgcn_mfma_f32_16x16x32_bf16(a, bb, pa, 0, 0, 0);
        }
        #pragma unroll
        for (int e = 0; e < 4; ++e)
            atomicAdd(&sAttn[(4 * lg + e) * DH + d0 + lm], pa[e]);
    }
    __syncthreads();

    OUT_A[((size_t)bh * LSEQ + i0 + (tid >> 6)) * DH + (tid & 63)] = sAttn[tid];
}

// ---------------- fallback (self-contained, from R2) ----------------

__global__ __launch_bounds__(NT, 4) void raa_fallback(
    const float* __restrict__ Q, const float* __restrict__ K,
    const float* __restrict__ V, const float* __restrict__ REL,
    const int* __restrict__ PM, const int* __restrict__ MASK,
    float* __restrict__ OUT_A, float* __restrict__ OUT_P)
{
    __shared__ ushort sQh[TI * 64];
    __shared__ ushort sQl[TI * 64];
    __shared__ float  sR[TI * NP];
    __shared__ ushort sPb[TI * 1024];
    __shared__ float  sAttn[TI * 64];
    __shared__ float  sRed[16 * 17];
    __shared__ float  sFin[16];

    const int tid = threadIdx.x;
    const int w  = tid >> 6;
    const int l  = tid & 63;
    const int lg = l >> 4;
    const int lm = l & 15;

    const int it = blockIdx.x, h = blockIdx.y, b = blockIdx.z;
    const int i0 = it * TI;

    const float* Qb0  = Q + ((size_t)b * NH + 0) * LSEQ * DH;
    const float* Qbh  = Q + ((size_t)b * NH + h) * LSEQ * DH;
    const float* Kbh  = K + ((size_t)b * NH + h) * LSEQ * DH;
    const float* Vbh  = V + ((size_t)b * NH + h) * LSEQ * DH;
    const float* RELb = REL + (size_t)b * NP * DH;
    const int*   PMb  = PM  + (size_t)b * LSEQ * LSEQ;
    const int*   MKb  = MASK + (size_t)b * LSEQ * LSEQ;

    {
        int row = tid >> 6, kk = tid & 63;
        float x = Qb0[(size_t)(i0 + row) * DH + kk];
        ushort hi = f2bf(x);
        ushort lo = f2bf(x - bf2f(hi));
        int ad = row * 64 + (((kk >> 3) ^ (row & 7)) << 3) + (kk & 7);
        sQh[ad] = hi; sQl[ad] = lo;
        sAttn[tid] = 0.f;
    }
    __syncthreads();

    bf16x8 qh[2], ql[2];
    #pragma unroll
    for (int ks = 0; ks < 2; ++ks) {
        int ch = lg + 4 * ks;
        int ad = lm * 64 + ((ch ^ (lm & 7)) << 3);
        qh[ks] = *(const bf16x8*)&sQh[ad];
        ql[ks] = *(const bf16x8*)&sQl[ad];
    }
    __syncthreads();

    {
        int row = tid >> 6, kk = tid & 63;
        float x = Qbh[(size_t)(i0 + row) * DH + kk];
        ushort hi = f2bf(x);
        ushort lo = f2bf(x - bf2f(hi));
        int ad = row * 64 + (((kk >> 3) ^ (row & 7)) << 3) + (kk & 7);
        sQh[ad] = hi; sQl[ad] = lo;
    }

    for (int ct = w; ct < 33; ct += 16) {
        int p0 = ct * 16;
        int prow = p0 + lm; if (prow > 512) prow = 512;
        const float* bsrc = RELb + (size_t)prow * DH + 8 * lg;
        f32x4 acc = {0.f, 0.f, 0.f, 0.f};
        #pragma unroll
        for (int ks = 0; ks < 2; ++ks) {
            float4 v0 = *(const float4*)(bsrc + ks * 32);
            float4 v1 = *(const float4*)(bsrc + ks * 32 + 4);
            float xs[8] = {v0.x, v0.y, v0.z, v0.w, v1.x, v1.y, v1.z, v1.w};
            bf16x8 bh, bl;
            #pragma unroll
            for (int e = 0; e < 8; ++e) {
                ushort hi = f2bf(xs[e]);
                bh[e] = (short)hi;
                bl[e] = (short)f2bf(xs[e] - bf2f(hi));
            }
            acc = __builtin_amdgcn_mfma_f32_16x16x32_bf16(qh[ks], bh, acc, 0, 0, 0);
            acc = __builtin_amdgcn_mfma_f32_16x16x32_bf16(ql[ks], bh, acc, 0, 0, 0);
            acc = __builtin_amdgcn_mfma_f32_16x16x32_bf16(qh[ks], bl, acc, 0, 0, 0);
        }
        int pcol = p0 + lm;
        if (pcol < NP) {
            #pragma unroll
            for (int e = 0; e < 4; ++e)
                sR[(4 * lg + e) * NP + pcol] = acc[e];
        }
    }
    __syncthreads();

    #pragma unroll
    for (int ks = 0; ks < 2; ++ks) {
        int ch = lg + 4 * ks;
        int ad = lm * 64 + ((ch ^ (lm & 7)) << 3);
        qh[ks] = *(const bf16x8*)&sQh[ad];
        ql[ks] = *(const bf16x8*)&sQl[ad];
    }
    f32x4 acc[4];
    #pragma unroll
    for (int t = 0; t < 4; ++t) {
        int j = (4 * w + t) * 16 + lm;
        const float* bsrc = Kbh + (size_t)j * DH + 8 * lg;
        acc[t] = (f32x4){0.f, 0.f, 0.f, 0.f};
        #pragma unroll
        for (int ks = 0; ks < 2; ++ks) {
            float4 v0 = *(const float4*)(bsrc + ks * 32);
            float4 v1 = *(const float4*)(bsrc + ks * 32 + 4);
            float xs[8] = {v0.x, v0.y, v0.z, v0.w, v1.x, v1.y, v1.z, v1.w};
            bf16x8 bh, bl;
            #pragma unroll
            for (int e = 0; e < 8; ++e) {
                ushort hi = f2bf(xs[e]);
                bh[e] = (short)hi;
                bl[e] = (short)f2bf(xs[e] - bf2f(hi));
            }
            acc[t] = __builtin_amdgcn_mfma_f32_16x16x32_bf16(qh[ks], bh, acc[t], 0, 0, 0);
            acc[t] = __builtin_amdgcn_mfma_f32_16x16x32_bf16(ql[ks], bh, acc[t], 0, 0, 0);
            acc[t] = __builtin_amdgcn_mfma_f32_16x16x32_bf16(qh[ks], bl, acc[t], 0, 0, 0);
        }
    }

    #pragma unroll
    for (int t = 0; t < 4; ++t) {
        int col = (4 * w + t) * 16 + lm;
        #pragma unroll
        for (int e = 0; e < 4; ++e) {
            int row = 4 * lg + e;
            size_t off = (size_t)(i0 + row) * LSEQ + col;
            int pm = PMb[off];
            int mk = MKb[off];
            float g = sR[row * NP + pm];
            acc[t][e] = (mk == 0) ? -1e9f : (acc[t][e] + g) * 0.125f;
        }
    }
    __syncthreads();
    for (int idx = tid; idx < TI * NP; idx += NT) sR[idx] = 0.f;
    __syncthreads();

    float Mr[4];
    #pragma unroll
    for (int e = 0; e < 4; ++e) {
        float m = fmaxf(fmaxf(acc[0][e], acc[1][e]), fmaxf(acc[2][e], acc[3][e]));
        #pragma unroll
        for (int o = 8; o >= 1; o >>= 1) m = fmaxf(m, __shfl_xor(m, o));
        Mr[e] = m;
    }
    if (lm == 0) {
        #pragma unroll
        for (int e = 0; e < 4; ++e) sRed[(4 * lg + e) * 17 + w] = Mr[e];
    }
    __syncthreads();
    if (w == 0 && l < 16) {
        float m = -INFINITY;
        for (int ww = 0; ww < 16; ++ww) m = fmaxf(m, sRed[l * 17 + ww]);
        sFin[l] = m;
    }
    __syncthreads();
    #pragma unroll
    for (int e = 0; e < 4; ++e) Mr[e] = sFin[4 * lg + e];

    float Sr[4];
    #pragma unroll
    for (int e = 0; e < 4; ++e) {
        float s = 0.f;
        #pragma unroll
        for (int t = 0; t < 4; ++t) {
            float v = __expf(acc[t][e] - Mr[e]);
            acc[t][e] = v;
            s += v;
        }
        #pragma unroll
        for (int o = 8; o >= 1; o >>= 1) s += __shfl_xor(s, o);
        Sr[e] = s;
    }
    if (lm == 0) {
        #pragma unroll
        for (int e = 0; e < 4; ++e) sRed[(4 * lg + e) * 17 + w] = Sr[e];
    }
    __syncthreads();
    if (w == 0 && l < 16) {
        float s = 0.f;
        for (int ww = 0; ww < 16; ++ww) s += sRed[l * 17 + ww];
        sFin[l] = s;
    }
    __syncthreads();

    float inv[4];
    #pragma unroll
    for (int e = 0; e < 4; ++e) inv[e] = 1.0f / sFin[4 * lg + e];

    const size_t pbase = (((size_t)b * NH + h) * LSEQ + i0) * LSEQ;
    #pragma unroll
    for (int t = 0; t < 4; ++t) {
        int col = (4 * w + t) * 16 + lm;
        #pragma unroll
        for (int e = 0; e < 4; ++e) {
            int row = 4 * lg + e;
            float p = acc[t][e] * inv[e];
            OUT_P[pbase + (size_t)row * LSEQ + col] = p;
            int ad = row * 1024 + (((col >> 3) ^ (row & 7)) << 3) + (col & 7);
            sPb[ad] = f2bf(p);
            int pm = PMb[(size_t)(i0 + row) * LSEQ + col];
            atomicAdd(&sR[row * NP + pm], p);
        }
    }
    __syncthreads();

    if (w < 8) {
        int ct = w >> 1, jh = w & 1;
        int d = ct * 16 + lm;
        f32x4 pa = {0.f, 0.f, 0.f, 0.f};
        for (int ks = 0; ks < 16; ++ks) {
            int j0 = jh * 512 + ks * 32;
            int ch = (j0 >> 3) + lg;
            bf16x8 a = *(const bf16x8*)&sPb[lm * 1024 + ((ch ^ (lm & 7)) << 3)];
            const float* vs = Vbh + (size_t)(j0 + 8 * lg) * DH + d;
            bf16x8 bb;
            #pragma unroll
            for (int e = 0; e < 8; ++e) bb[e] = (short)f2bf(vs[(size_t)e * DH]);
            pa = __builtin_amdgcn_mfma_f32_16x16x32_bf16(a, bb, pa, 0, 0, 0);
        }
        #pragma unroll
        for (int e = 0; e < 4; ++e)
            atomicAdd(&sAttn[(4 * lg + e) * 64 + d], pa[e]);
    } else {
        int ct = (w - 8) >> 1, ph = w & 1;
        int d = ct * 16 + lm;
        int nks = ph ? 9 : 8;
        f32x4 pa = {0.f, 0.f, 0.f, 0.f};
        for (int ks = 0; ks < nks; ++ks) {
            int p0 = ph * 256 + ks * 32 + 8 * lg;
            bf16x8 a, bb;
            #pragma unroll
            for (int e = 0; e < 8; ++e) {
                int pp = p0 + e;
                float av = (pp < NP) ? sR[lm * NP + pp] : 0.f;
                a[e] = (short)f2bf(av);
                int pc = (pp < NP) ? pp : (NP - 1);
                bb[e] = (short)f2bf(RELb[(size_t)pc * DH + d]);
            }
            pa = __builtin_amdgcn_mfma_f32_16x16x32_bf16(a, bb, pa, 0, 0, 0);
        }
        #pragma unroll
        for (int e = 0; e < 4; ++e)
            atomicAdd(&sAttn[(4 * lg + e) * 64 + d], pa[e]);
    }
    __syncthreads();

    {
        int row = tid >> 6, col = tid & 63;
        OUT_A[(((size_t)b * NH + h) * LSEQ + i0 + row) * DH + col] =
            sAttn[row * 64 + col];
    }
}

extern "C" void kernel_launch(void* const* d_in, const int* in_sizes, int n_in,
                              void* d_out, int out_size, void* d_ws, size_t ws_size,
                              hipStream_t stream) {
    const float* q    = (const float*)d_in[0];
    const float* k    = (const float*)d_in[1];
    const float* v    = (const float*)d_in[2];
    const float* rel  = (const float*)d_in[3];
    const int*   pm   = (const int*)d_in[4];
    const int*   mask = (const int*)d_in[5];
    float* out_a = (float*)d_out;
    float* out_p = (float*)d_out + (size_t)BSZ * NH * LSEQ * DH;

    dim3 grid(LSEQ / TI, NH, BSZ);
    if (ws_size >= WS_NEED && d_ws != nullptr) {
        ushort* ws = (ushort*)d_ws;
        prep1<<<NB_P1, 256, 0, stream>>>(q, k, v, rel, ws);
        prep2<<<1024, 256, 0, stream>>>(pm, mask, ws);
        raa_main<<<grid, NT, 0, stream>>>((const ushort*)ws, out_a, out_p);
    } else {
        raa_fallback<<<grid, NT, 0, stream>>>(q, k, v, rel, pm, mask, out_a, out_p);
    }
}

// Round 6
// 474.108 us; speedup vs baseline: 3.3239x; 1.1718x over previous
//
#include <hip/hip_runtime.h>

// RelationAwareAttention: BS=4,H=8,L=1024,D=64,P=513, fp32 in/out.
// out = [attn_sum (B,H,L,D) | p_attn (B,H,L,L)] flat fp32.
//
// R6: prep1 (job-split, SR first): SR score_r table; Qh/Ql,Kh/Kl bf16 planes;
//     Vt (V^T bf16); Rt (REL^T bf16 padded).  prep2: GP packed gather table.
//     Kernel A (XCD-swizzled): QK^T + softmax + fp32 p_attn store, no big LDS.
//     Kernel B (XCD-swizzled): bucket scatter (LDS atomics) + p@V + buckets@REL
//     reading p_attn back (L2/L3-warm).  Fallback if ws too small.

#define BSZ 4
#define NH 8
#define LSEQ 1024
#define DH 64
#define NP 513
#define TI 16
#define SRX 548            // LDS bucket row stride (floats): 16B-aligned
#define RTC 544            // Rt padded cols

#define NQE (BSZ*NH*LSEQ*DH)   // 2097152 elems per plane
#define NRT (BSZ*DH*RTC)       // 139264
#define NSR (BSZ*LSEQ*NP)      // 2101248
#define NGPW (2*BSZ*LSEQ*LSEQ) // GP span in ushort units
#define OFF_QH 0
#define OFF_QL (NQE)
#define OFF_KH (2*NQE)
#define OFF_KL (3*NQE)
#define OFF_VT (4*NQE)
#define OFF_RT (5*NQE)
#define OFF_SR (5*NQE + NRT)
#define OFF_GP (5*NQE + NRT + NSR)
#define WS_NEED ((size_t)(OFF_GP + NGPW) * 2)

#define NB_SR 512
#define NB_QK 4096
#define NB_VT 512
#define NB_RT 544
#define NB_P1 (NB_SR + NB_QK + NB_VT + NB_RT)

typedef __attribute__((ext_vector_type(8))) short bf16x8;
typedef __attribute__((ext_vector_type(4))) float f32x4;
typedef __attribute__((ext_vector_type(4))) ushort u16x4;
typedef __attribute__((ext_vector_type(4))) uint u32x4;

__device__ __forceinline__ ushort f2bf(float x) {
    uint u = __float_as_uint(x);
    u += 0x7FFFu + ((u >> 16) & 1u);
    return (ushort)(u >> 16);
}
__device__ __forceinline__ float bf2f(ushort h) {
    return __uint_as_float(((uint)h) << 16);
}

// ---------------- prep1: SR | qk planes | vt | rt (SR dispatched first) ------

__global__ __launch_bounds__(256) void prep1(
    const float* __restrict__ Q, const float* __restrict__ K,
    const float* __restrict__ V, const float* __restrict__ REL,
    ushort* __restrict__ ws)
{
    __shared__ float sT[64 * 65];
    const int bid = blockIdx.x;
    const int tid = threadIdx.x;

    if (bid < NB_SR) {
        // ---- job SR: score_r = Q(head0) . REL^T, bf16 table (once per b) ----
        const int b = bid >> 7;
        const int r = bid & 127;
        const int it = r >> 1, half = r & 1;
        const int i0 = it * TI;
        const int w = tid >> 6, l = tid & 63, lg = l >> 4, lm = l & 15;

        const float* Qb0 = Q + ((size_t)b * NH) * LSEQ * DH;
        const float* RELb = REL + (size_t)b * NP * DH;
        ushort* SRb = ws + OFF_SR + (size_t)b * LSEQ * NP;

        bf16x8 qh[2], ql[2];
        #pragma unroll
        for (int ks = 0; ks < 2; ++ks) {
            const float* qs = Qb0 + (size_t)(i0 + lm) * DH + ks * 32 + lg * 8;
            float4 v0 = *(const float4*)(qs);
            float4 v1 = *(const float4*)(qs + 4);
            float xs[8] = {v0.x, v0.y, v0.z, v0.w, v1.x, v1.y, v1.z, v1.w};
            #pragma unroll
            for (int e = 0; e < 8; ++e) {
                ushort hi = f2bf(xs[e]);
                qh[ks][e] = (short)hi;
                ql[ks][e] = (short)f2bf(xs[e] - bf2f(hi));
            }
        }

        int ctb = half ? 33 : 16;
        for (int ct = half * 16 + w; ct < ctb; ct += 4) {
            int p0 = ct * 16;
            int prow = p0 + lm; if (prow > 512) prow = 512;
            f32x4 a0 = {0.f, 0.f, 0.f, 0.f};
            #pragma unroll
            for (int ks = 0; ks < 2; ++ks) {
                const float* bsrc = RELb + (size_t)prow * DH + ks * 32 + lg * 8;
                float4 v0 = *(const float4*)(bsrc);
                float4 v1 = *(const float4*)(bsrc + 4);
                float xs[8] = {v0.x, v0.y, v0.z, v0.w, v1.x, v1.y, v1.z, v1.w};
                bf16x8 bh8, bl8;
                #pragma unroll
                for (int e = 0; e < 8; ++e) {
                    ushort hi = f2bf(xs[e]);
                    bh8[e] = (short)hi;
                    bl8[e] = (short)f2bf(xs[e] - bf2f(hi));
                }
                a0 = __builtin_amdgcn_mfma_f32_16x16x32_bf16(qh[ks], bh8, a0, 0, 0, 0);
                a0 = __builtin_amdgcn_mfma_f32_16x16x32_bf16(ql[ks], bh8, a0, 0, 0, 0);
                a0 = __builtin_amdgcn_mfma_f32_16x16x32_bf16(qh[ks], bl8, a0, 0, 0, 0);
            }
            if (p0 + lm < NP) {
                #pragma unroll
                for (int e = 0; e < 4; ++e)
                    SRb[(size_t)(i0 + 4 * lg + e) * NP + p0 + lm] = f2bf(a0[e]);
            }
        }
    } else if (bid < NB_SR + NB_QK) {
        // ---- job QK: Q/K -> bf16 hi/lo planes ----
        const int n4 = NQE / 4;
        int i = (bid - NB_SR) * 256 + tid;
        int isK = i >= n4;
        int base = i - isK * n4;
        float4 v = ((const float4*)(isK ? K : Q))[base];
        float xs[4] = {v.x, v.y, v.z, v.w};
        u16x4 hh, ll;
        #pragma unroll
        for (int e = 0; e < 4; ++e) {
            ushort hi = f2bf(xs[e]);
            hh[e] = hi;
            ll[e] = f2bf(xs[e] - bf2f(hi));
        }
        *(u16x4*)(ws + (isK ? OFF_KH : OFF_QH) + (size_t)base * 4) = hh;
        *(u16x4*)(ws + (isK ? OFF_KL : OFF_QL) + (size_t)base * 4) = ll;
    } else if (bid < NB_SR + NB_QK + NB_VT) {
        // ---- job VT: V transpose (LDS tile) ----
        const int vb = bid - (NB_SR + NB_QK);
        const int bh = vb >> 4;
        const int j0 = (vb & 15) * 64;
        const float* Vb = V + ((size_t)bh << 16);
        for (int i = tid; i < 1024; i += 256) {
            int jr = i >> 4, c4 = i & 15;
            float4 vv = *(const float4*)(Vb + (size_t)(j0 + jr) * DH + c4 * 4);
            float* dst = &sT[jr * 65 + c4 * 4];
            dst[0] = vv.x; dst[1] = vv.y; dst[2] = vv.z; dst[3] = vv.w;
        }
        __syncthreads();
        const int d = tid >> 2, jseg = tid & 3;
        ushort* dst = ws + OFF_VT + ((size_t)bh << 16) + (size_t)d * LSEQ + j0 + jseg * 16;
        #pragma unroll
        for (int g = 0; g < 4; ++g) {
            u16x4 o;
            #pragma unroll
            for (int e = 0; e < 4; ++e)
                o[e] = f2bf(sT[(jseg * 16 + g * 4 + e) * 65 + d]);
            *(u16x4*)(dst + g * 4) = o;
        }
    } else {
        // ---- job RT: REL transpose (padded) ----
        int i = (bid - (NB_SR + NB_QK + NB_VT)) * 256 + tid;
        int b = i / (DH * RTC);
        int r = i - b * (DH * RTC);
        int d = r / RTC;
        int p = r - d * RTC;
        float x = (p < NP) ? REL[((size_t)b * NP + p) * DH + d] : 0.f;
        ws[OFF_RT + i] = f2bf(x);
    }
}

// ---------------- prep2: GP = packed (bf16 gathered score_r | u16 pm) --------

__global__ __launch_bounds__(256) void prep2(
    const int* __restrict__ PM, const int* __restrict__ MASK,
    ushort* __restrict__ ws)
{
    __shared__ ushort sSR[4 * 520];
    const int tid = threadIdx.x;
    const int bid = blockIdx.x;
    const int b = bid >> 8;
    const int row0 = (bid & 255) * 4;

    const ushort* SRb = ws + OFF_SR + (size_t)b * LSEQ * NP;
    uint* GPb = (uint*)(ws + OFF_GP) + (size_t)b * LSEQ * LSEQ;
    const int* PMb = PM + (size_t)b * LSEQ * LSEQ;
    const int* MKb = MASK + (size_t)b * LSEQ * LSEQ;

    for (int i = tid; i < 4 * 520; i += 256) {
        int row = i / 520, col = i - row * 520;
        if (col < NP) sSR[row * 520 + col] = SRb[(size_t)(row0 + row) * NP + col];
    }
    __syncthreads();

    #pragma unroll
    for (int r = 0; r < 4; ++r) {
        int idx4 = r * 256 + tid;
        int row = idx4 >> 8;
        int c0 = (idx4 & 255) * 4;
        size_t off = (size_t)(row0 + row) * LSEQ + c0;
        int4 pm4 = *(const int4*)(PMb + off);
        int4 mk4 = *(const int4*)(MKb + off);
        const ushort* srow = &sSR[row * 520];
        u32x4 o;
        o[0] = ((uint)(mk4.x ? srow[pm4.x] : 0xFF62u) << 16) | (uint)pm4.x;
        o[1] = ((uint)(mk4.y ? srow[pm4.y] : 0xFF62u) << 16) | (uint)pm4.y;
        o[2] = ((uint)(mk4.z ? srow[pm4.z] : 0xFF62u) << 16) | (uint)pm4.z;
        o[3] = ((uint)(mk4.w ? srow[pm4.w] : 0xFF62u) << 16) | (uint)pm4.w;
        *(u32x4*)(GPb + off) = o;
    }
}

// ---------------- kernel A: QK^T + softmax + fp32 p_attn ----------------

__global__ __launch_bounds__(512, 4) void raa_qks(
    const ushort* __restrict__ ws, float* __restrict__ OUT_P)
{
    __shared__ float sRedM[16 * 9];
    __shared__ float sRedS[16 * 9];

    const int tid = threadIdx.x;
    const int w  = tid >> 6;        // 0..7
    const int l  = tid & 63;
    const int lg = l >> 4;
    const int lm = l & 15;

    // XCD-aware decode: xcd = bid&7 owns 4 (b,h) panels x 64 i-tiles
    const int bid = blockIdx.x;
    const int xcd = bid & 7;
    const int idx = bid >> 3;
    const int bh  = (xcd << 2) + (idx >> 6);
    const int it  = idx & 63;
    const int b   = bh >> 3;
    const int i0  = it * TI;

    const ushort* Qh = ws + OFF_QH + (size_t)bh * LSEQ * DH;
    const ushort* Ql = ws + OFF_QL + (size_t)bh * LSEQ * DH;
    const ushort* Kh = ws + OFF_KH + (size_t)bh * LSEQ * DH;
    const ushort* Kl = ws + OFF_KL + (size_t)bh * LSEQ * DH;
    const uint*   GPb = (const uint*)(ws + OFF_GP) + (size_t)b * LSEQ * LSEQ;

    // gathered scores (mask folded), front-loaded
    float gf[32];
    #pragma unroll
    for (int t = 0; t < 8; ++t) {
        #pragma unroll
        for (int e = 0; e < 4; ++e) {
            int col = (8 * w + t) * 16 + lm;
            int row = 4 * lg + e;
            uint g = GPb[(size_t)(i0 + row) * LSEQ + col];
            gf[t * 4 + e] = bf2f((ushort)(g >> 16));
        }
    }

    bf16x8 qhh[2], qhl[2];
    #pragma unroll
    for (int ks = 0; ks < 2; ++ks) {
        size_t ao = (size_t)(i0 + lm) * DH + ks * 32 + lg * 8;
        qhh[ks] = *(const bf16x8*)(Qh + ao);
        qhl[ks] = *(const bf16x8*)(Ql + ao);
    }

    // QK^T: 8 coltiles per wave
    f32x4 acc[8];
    #pragma unroll
    for (int t = 0; t < 8; ++t) {
        size_t bo = (size_t)((8 * w + t) * 16 + lm) * DH + lg * 8;
        bf16x8 kh0 = *(const bf16x8*)(Kh + bo);
        bf16x8 kl0 = *(const bf16x8*)(Kl + bo);
        bf16x8 kh1 = *(const bf16x8*)(Kh + bo + 32);
        bf16x8 kl1 = *(const bf16x8*)(Kl + bo + 32);
        f32x4 a = {0.f, 0.f, 0.f, 0.f};
        a = __builtin_amdgcn_mfma_f32_16x16x32_bf16(qhh[0], kh0, a, 0, 0, 0);
        a = __builtin_amdgcn_mfma_f32_16x16x32_bf16(qhl[0], kh0, a, 0, 0, 0);
        a = __builtin_amdgcn_mfma_f32_16x16x32_bf16(qhh[0], kl0, a, 0, 0, 0);
        a = __builtin_amdgcn_mfma_f32_16x16x32_bf16(qhh[1], kh1, a, 0, 0, 0);
        a = __builtin_amdgcn_mfma_f32_16x16x32_bf16(qhl[1], kh1, a, 0, 0, 0);
        a = __builtin_amdgcn_mfma_f32_16x16x32_bf16(qhh[1], kl1, a, 0, 0, 0);
        acc[t] = a;
    }

    // gather + mask + scale
    #pragma unroll
    for (int i = 0; i < 32; ++i) {
        int t = i >> 2, e = i & 3;
        float g = gf[i];
        acc[t][e] = (g < -1e30f) ? -1e9f : (acc[t][e] + g) * 0.125f;
    }

    // softmax: wave-local (m,s), one barrier, 8-lane combine
    float mw[4], c4v[4];
    #pragma unroll
    for (int e = 0; e < 4; ++e) {
        float m = acc[0][e];
        #pragma unroll
        for (int t = 1; t < 8; ++t) m = fmaxf(m, acc[t][e]);
        #pragma unroll
        for (int o = 8; o >= 1; o >>= 1) m = fmaxf(m, __shfl_xor(m, o));
        mw[e] = m;
        float s = 0.f;
        #pragma unroll
        for (int t = 0; t < 8; ++t) {
            float v = __expf(acc[t][e] - m);
            acc[t][e] = v;
            s += v;
        }
        #pragma unroll
        for (int o = 8; o >= 1; o >>= 1) s += __shfl_xor(s, o);
        if (lm == 0) {
            sRedM[(4 * lg + e) * 9 + w] = m;
            sRedS[(4 * lg + e) * 9 + w] = s;
        }
    }
    __syncthreads();
    #pragma unroll
    for (int e = 0; e < 4; ++e) {
        int row = 4 * lg + e;
        float mv = sRedM[row * 9 + (lm & 7)];
        float sv = sRedS[row * 9 + (lm & 7)];
        float m = mv;
        #pragma unroll
        for (int o = 4; o >= 1; o >>= 1) m = fmaxf(m, __shfl_xor(m, o));
        float sp = sv * __expf(mv - m);
        #pragma unroll
        for (int o = 4; o >= 1; o >>= 1) sp += __shfl_xor(sp, o);
        c4v[e] = __expf(mw[e] - m) / sp;
    }

    // fp32 p_attn store (4x64B segments per wave-instr)
    const size_t pbase = ((size_t)bh * LSEQ + i0) * LSEQ;
    #pragma unroll
    for (int t = 0; t < 8; ++t) {
        int col = (8 * w + t) * 16 + lm;
        #pragma unroll
        for (int e = 0; e < 4; ++e) {
            int row = 4 * lg + e;
            OUT_P[pbase + (size_t)row * LSEQ + col] = acc[t][e] * c4v[e];
        }
    }
}

// ---------------- kernel B: scatter + p@V + buckets@REL ----------------

__global__ __launch_bounds__(512, 4) void raa_pv(
    const ushort* __restrict__ ws, const float* __restrict__ P_in,
    float* __restrict__ OUT_A)
{
    __shared__ float X[TI * SRX];       // 35.1 KB buckets
    __shared__ float sAttn[TI * DH];    // 4 KB

    const int tid = threadIdx.x;
    const int w  = tid >> 6;
    const int l  = tid & 63;
    const int lg = l >> 4;
    const int lm = l & 15;

    const int bid = blockIdx.x;
    const int xcd = bid & 7;
    const int idx = bid >> 3;
    const int bh  = (xcd << 2) + (idx >> 6);
    const int it  = idx & 63;
    const int b   = bh >> 3;
    const int i0  = it * TI;

    const ushort* Vt = ws + OFF_VT + (size_t)bh * DH * LSEQ;
    const ushort* Rt = ws + OFF_RT + (size_t)b * DH * RTC;
    const uint*   GPb = (const uint*)(ws + OFF_GP) + (size_t)b * LSEQ * LSEQ;
    const float*  Pb = P_in + ((size_t)bh * LSEQ + i0) * LSEQ;

    for (int z = tid; z < TI * SRX; z += 512) X[z] = 0.f;
    for (int z = tid; z < TI * DH; z += 512) sAttn[z] = 0.f;
    __syncthreads();

    // scatter: wave w owns rows 2w,2w+1; half-wave per row, vectorized
    {
        int row = 2 * w + (l >> 5);
        int l32 = l & 31;
        const float* prow = Pb + (size_t)row * LSEQ;
        const uint*  grow = GPb + (size_t)(i0 + row) * LSEQ;
        float* xrow = &X[row * SRX];
        #pragma unroll
        for (int itr = 0; itr < 8; ++itr) {
            int c0 = itr * 128 + l32 * 4;
            float4 p4 = *(const float4*)(prow + c0);
            u32x4 g4 = *(const u32x4*)(grow + c0);
            atomicAdd(&xrow[g4[0] & 0xFFFFu], p4.x);
            atomicAdd(&xrow[g4[1] & 0xFFFFu], p4.y);
            atomicAdd(&xrow[g4[2] & 0xFFFFu], p4.z);
            atomicAdd(&xrow[g4[3] & 0xFFFFu], p4.w);
        }
    }
    __syncthreads();

    // waves 0-3: p@V; waves 4-7: buckets@REL; both d-quartered
    const int d0 = (w & 3) * 16;
    f32x4 pa = {0.f, 0.f, 0.f, 0.f};
    if (w < 4) {
        #pragma unroll 4
        for (int ks = 0; ks < 32; ++ks) {
            int j0 = ks * 32;
            const float* ps = Pb + (size_t)lm * LSEQ + j0 + lg * 8;
            float4 a0 = *(const float4*)(ps);
            float4 a1 = *(const float4*)(ps + 4);
            bf16x8 a;
            a[0] = (short)f2bf(a0.x); a[1] = (short)f2bf(a0.y);
            a[2] = (short)f2bf(a0.z); a[3] = (short)f2bf(a0.w);
            a[4] = (short)f2bf(a1.x); a[5] = (short)f2bf(a1.y);
            a[6] = (short)f2bf(a1.z); a[7] = (short)f2bf(a1.w);
            bf16x8 bb = *(const bf16x8*)(Vt + (size_t)(d0 + lm) * LSEQ + j0 + lg * 8);
            pa = __builtin_amdgcn_mfma_f32_16x16x32_bf16(a, bb, pa, 0, 0, 0);
        }
    } else {
        #pragma unroll 4
        for (int ks = 0; ks < 17; ++ks) {
            int p0 = ks * 32;
            const float* xs = &X[lm * SRX + p0 + lg * 8];
            float4 a0 = *(const float4*)(xs);
            float4 a1 = *(const float4*)(xs + 4);
            bf16x8 a;
            a[0] = (short)f2bf(a0.x); a[1] = (short)f2bf(a0.y);
            a[2] = (short)f2bf(a0.z); a[3] = (short)f2bf(a0.w);
            a[4] = (short)f2bf(a1.x); a[5] = (short)f2bf(a1.y);
            a[6] = (short)f2bf(a1.z); a[7] = (short)f2bf(a1.w);
            bf16x8 bb = *(const bf16x8*)(Rt + (size_t)(d0 + lm) * RTC + p0 + lg * 8);
            pa = __builtin_amdgcn_mfma_f32_16x16x32_bf16(a, bb, pa, 0, 0, 0);
        }
    }
    #pragma unroll
    for (int e = 0; e < 4; ++e)
        atomicAdd(&sAttn[(4 * lg + e) * DH + d0 + lm], pa[e]);
    __syncthreads();

    {
        int row = tid >> 5;
        int c0 = (tid & 31) * 2;
        *(float2*)(OUT_A + ((size_t)bh * LSEQ + i0 + row) * DH + c0) =
            *(const float2*)&sAttn[row * DH + c0];
    }
}

// ---------------- fallback (self-contained, from R2) ----------------

__global__ __launch_bounds__(1024, 4) void raa_fallback(
    const float* __restrict__ Q, const float* __restrict__ K,
    const float* __restrict__ V, const float* __restrict__ REL,
    const int* __restrict__ PM, const int* __restrict__ MASK,
    float* __restrict__ OUT_A, float* __restrict__ OUT_P)
{
    __shared__ ushort sQh[TI * 64];
    __shared__ ushort sQl[TI * 64];
    __shared__ float  sR[TI * NP];
    __shared__ ushort sPb[TI * 1024];
    __shared__ float  sAttn[TI * 64];
    __shared__ float  sRed[16 * 17];
    __shared__ float  sFin[16];

    const int tid = threadIdx.x;
    const int w  = tid >> 6;
    const int l  = tid & 63;
    const int lg = l >> 4;
    const int lm = l & 15;

    const int it = blockIdx.x, h = blockIdx.y, b = blockIdx.z;
    const int i0 = it * TI;

    const float* Qb0  = Q + ((size_t)b * NH + 0) * LSEQ * DH;
    const float* Qbh  = Q + ((size_t)b * NH + h) * LSEQ * DH;
    const float* Kbh  = K + ((size_t)b * NH + h) * LSEQ * DH;
    const float* Vbh  = V + ((size_t)b * NH + h) * LSEQ * DH;
    const float* RELb = REL + (size_t)b * NP * DH;
    const int*   PMb  = PM  + (size_t)b * LSEQ * LSEQ;
    const int*   MKb  = MASK + (size_t)b * LSEQ * LSEQ;

    {
        int row = tid >> 6, kk = tid & 63;
        float x = Qb0[(size_t)(i0 + row) * DH + kk];
        ushort hi = f2bf(x);
        ushort lo = f2bf(x - bf2f(hi));
        int ad = row * 64 + (((kk >> 3) ^ (row & 7)) << 3) + (kk & 7);
        sQh[ad] = hi; sQl[ad] = lo;
        sAttn[tid] = 0.f;
    }
    __syncthreads();

    bf16x8 qh[2], ql[2];
    #pragma unroll
    for (int ks = 0; ks < 2; ++ks) {
        int ch = lg + 4 * ks;
        int ad = lm * 64 + ((ch ^ (lm & 7)) << 3);
        qh[ks] = *(const bf16x8*)&sQh[ad];
        ql[ks] = *(const bf16x8*)&sQl[ad];
    }
    __syncthreads();

    {
        int row = tid >> 6, kk = tid & 63;
        float x = Qbh[(size_t)(i0 + row) * DH + kk];
        ushort hi = f2bf(x);
        ushort lo = f2bf(x - bf2f(hi));
        int ad = row * 64 + (((kk >> 3) ^ (row & 7)) << 3) + (kk & 7);
        sQh[ad] = hi; sQl[ad] = lo;
    }

    for (int ct = w; ct < 33; ct += 16) {
        int p0 = ct * 16;
        int prow = p0 + lm; if (prow > 512) prow = 512;
        const float* bsrc = RELb + (size_t)prow * DH + 8 * lg;
        f32x4 acc = {0.f, 0.f, 0.f, 0.f};
        #pragma unroll
        for (int ks = 0; ks < 2; ++ks) {
            float4 v0 = *(const float4*)(bsrc + ks * 32);
            float4 v1 = *(const float4*)(bsrc + ks * 32 + 4);
            float xs[8] = {v0.x, v0.y, v0.z, v0.w, v1.x, v1.y, v1.z, v1.w};
            bf16x8 bh, bl;
            #pragma unroll
            for (int e = 0; e < 8; ++e) {
                ushort hi = f2bf(xs[e]);
                bh[e] = (short)hi;
                bl[e] = (short)f2bf(xs[e] - bf2f(hi));
            }
            acc = __builtin_amdgcn_mfma_f32_16x16x32_bf16(qh[ks], bh, acc, 0, 0, 0);
            acc = __builtin_amdgcn_mfma_f32_16x16x32_bf16(ql[ks], bh, acc, 0, 0, 0);
            acc = __builtin_amdgcn_mfma_f32_16x16x32_bf16(qh[ks], bl, acc, 0, 0, 0);
        }
        int pcol = p0 + lm;
        if (pcol < NP) {
            #pragma unroll
            for (int e = 0; e < 4; ++e)
                sR[(4 * lg + e) * NP + pcol] = acc[e];
        }
    }
    __syncthreads();

    #pragma unroll
    for (int ks = 0; ks < 2; ++ks) {
        int ch = lg + 4 * ks;
        int ad = lm * 64 + ((ch ^ (lm & 7)) << 3);
        qh[ks] = *(const bf16x8*)&sQh[ad];
        ql[ks] = *(const bf16x8*)&sQl[ad];
    }
    f32x4 acc[4];
    #pragma unroll
    for (int t = 0; t < 4; ++t) {
        int j = (4 * w + t) * 16 + lm;
        const float* bsrc = Kbh + (size_t)j * DH + 8 * lg;
        acc[t] = (f32x4){0.f, 0.f, 0.f, 0.f};
        #pragma unroll
        for (int ks = 0; ks < 2; ++ks) {
            float4 v0 = *(const float4*)(bsrc + ks * 32);
            float4 v1 = *(const float4*)(bsrc + ks * 32 + 4);
            float xs[8] = {v0.x, v0.y, v0.z, v0.w, v1.x, v1.y, v1.z, v1.w};
            bf16x8 bh, bl;
            #pragma unroll
            for (int e = 0; e < 8; ++e) {
                ushort hi = f2bf(xs[e]);
                bh[e] = (short)hi;
                bl[e] = (short)f2bf(xs[e] - bf2f(hi));
            }
            acc[t] = __builtin_amdgcn_mfma_f32_16x16x32_bf16(qh[ks], bh, acc[t], 0, 0, 0);
            acc[t] = __builtin_amdgcn_mfma_f32_16x16x32_bf16(ql[ks], bh, acc[t], 0, 0, 0);
            acc[t] = __builtin_amdgcn_mfma_f32_16x16x32_bf16(qh[ks], bl, acc[t], 0, 0, 0);
        }
    }

    #pragma unroll
    for (int t = 0; t < 4; ++t) {
        int col = (4 * w + t) * 16 + lm;
        #pragma unroll
        for (int e = 0; e < 4; ++e) {
            int row = 4 * lg + e;
            size_t off = (size_t)(i0 + row) * LSEQ + col;
            int pm = PMb[off];
            int mk = MKb[off];
            float g = sR[row * NP + pm];
            acc[t][e] = (mk == 0) ? -1e9f : (acc[t][e] + g) * 0.125f;
        }
    }
    __syncthreads();
    for (int idxx = tid; idxx < TI * NP; idxx += 1024) sR[idxx] = 0.f;
    __syncthreads();

    float Mr[4];
    #pragma unroll
    for (int e = 0; e < 4; ++e) {
        float m = fmaxf(fmaxf(acc[0][e], acc[1][e]), fmaxf(acc[2][e], acc[3][e]));
        #pragma unroll
        for (int o = 8; o >= 1; o >>= 1) m = fmaxf(m, __shfl_xor(m, o));
        Mr[e] = m;
    }
    if (lm == 0) {
        #pragma unroll
        for (int e = 0; e < 4; ++e) sRed[(4 * lg + e) * 17 + w] = Mr[e];
    }
    __syncthreads();
    if (w == 0 && l < 16) {
        float m = -INFINITY;
        for (int ww = 0; ww < 16; ++ww) m = fmaxf(m, sRed[l * 17 + ww]);
        sFin[l] = m;
    }
    __syncthreads();
    #pragma unroll
    for (int e = 0; e < 4; ++e) Mr[e] = sFin[4 * lg + e];

    float Sr[4];
    #pragma unroll
    for (int e = 0; e < 4; ++e) {
        float s = 0.f;
        #pragma unroll
        for (int t = 0; t < 4; ++t) {
            float v = __expf(acc[t][e] - Mr[e]);
            acc[t][e] = v;
            s += v;
        }
        #pragma unroll
        for (int o = 8; o >= 1; o >>= 1) s += __shfl_xor(s, o);
        Sr[e] = s;
    }
    if (lm == 0) {
        #pragma unroll
        for (int e = 0; e < 4; ++e) sRed[(4 * lg + e) * 17 + w] = Sr[e];
    }
    __syncthreads();
    if (w == 0 && l < 16) {
        float s = 0.f;
        for (int ww = 0; ww < 16; ++ww) s += sRed[l * 17 + ww];
        sFin[l] = s;
    }
    __syncthreads();

    float inv[4];
    #pragma unroll
    for (int e = 0; e < 4; ++e) inv[e] = 1.0f / sFin[4 * lg + e];

    const size_t pbase = (((size_t)b * NH + h) * LSEQ + i0) * LSEQ;
    #pragma unroll
    for (int t = 0; t < 4; ++t) {
        int col = (4 * w + t) * 16 + lm;
        #pragma unroll
        for (int e = 0; e < 4; ++e) {
            int row = 4 * lg + e;
            float p = acc[t][e] * inv[e];
            OUT_P[pbase + (size_t)row * LSEQ + col] = p;
            int ad = row * 1024 + (((col >> 3) ^ (row & 7)) << 3) + (col & 7);
            sPb[ad] = f2bf(p);
            int pm = PMb[(size_t)(i0 + row) * LSEQ + col];
            atomicAdd(&sR[row * NP + pm], p);
        }
    }
    __syncthreads();

    if (w < 8) {
        int ct = w >> 1, jh = w & 1;
        int d = ct * 16 + lm;
        f32x4 pa = {0.f, 0.f, 0.f, 0.f};
        for (int ks = 0; ks < 16; ++ks) {
            int j0 = jh * 512 + ks * 32;
            int ch = (j0 >> 3) + lg;
            bf16x8 a = *(const bf16x8*)&sPb[lm * 1024 + ((ch ^ (lm & 7)) << 3)];
            const float* vs = Vbh + (size_t)(j0 + 8 * lg) * DH + d;
            bf16x8 bb;
            #pragma unroll
            for (int e = 0; e < 8; ++e) bb[e] = (short)f2bf(vs[(size_t)e * DH]);
            pa = __builtin_amdgcn_mfma_f32_16x16x32_bf16(a, bb, pa, 0, 0, 0);
        }
        #pragma unroll
        for (int e = 0; e < 4; ++e)
            atomicAdd(&sAttn[(4 * lg + e) * 64 + d], pa[e]);
    } else {
        int ct = (w - 8) >> 1, ph = w & 1;
        int d = ct * 16 + lm;
        int nks = ph ? 9 : 8;
        f32x4 pa = {0.f, 0.f, 0.f, 0.f};
        for (int ks = 0; ks < nks; ++ks) {
            int p0 = ph * 256 + ks * 32 + 8 * lg;
            bf16x8 a, bb;
            #pragma unroll
            for (int e = 0; e < 8; ++e) {
                int pp = p0 + e;
                float av = (pp < NP) ? sR[lm * NP + pp] : 0.f;
                a[e] = (short)f2bf(av);
                int pc = (pp < NP) ? pp : (NP - 1);
                bb[e] = (short)f2bf(RELb[(size_t)pc * DH + d]);
            }
            pa = __builtin_amdgcn_mfma_f32_16x16x32_bf16(a, bb, pa, 0, 0, 0);
        }
        #pragma unroll
        for (int e = 0; e < 4; ++e)
            atomicAdd(&sAttn[(4 * lg + e) * 64 + d], pa[e]);
    }
    __syncthreads();

    {
        int row = tid >> 6, col = tid & 63;
        OUT_A[(((size_t)b * NH + h) * LSEQ + i0 + row) * DH + col] =
            sAttn[row * 64 + col];
    }
}

extern "C" void kernel_launch(void* const* d_in, const int* in_sizes, int n_in,
                              void* d_out, int out_size, void* d_ws, size_t ws_size,
                              hipStream_t stream) {
    const float* q    = (const float*)d_in[0];
    const float* k    = (const float*)d_in[1];
    const float* v    = (const float*)d_in[2];
    const float* rel  = (const float*)d_in[3];
    const int*   pm   = (const int*)d_in[4];
    const int*   mask = (const int*)d_in[5];
    float* out_a = (float*)d_out;
    float* out_p = (float*)d_out + (size_t)BSZ * NH * LSEQ * DH;

    if (ws_size >= WS_NEED && d_ws != nullptr) {
        ushort* ws = (ushort*)d_ws;
        prep1<<<NB_P1, 256, 0, stream>>>(q, k, v, rel, ws);
        prep2<<<1024, 256, 0, stream>>>(pm, mask, ws);
        raa_qks<<<2048, 512, 0, stream>>>((const ushort*)ws, out_p);
        raa_pv<<<2048, 512, 0, stream>>>((const ushort*)ws, out_p, out_a);
    } else {
        dim3 grid(LSEQ / TI, NH, BSZ);
        raa_fallback<<<grid, 1024, 0, stream>>>(q, k, v, rel, pm, mask, out_a, out_p);
    }
}